// Round 12
// baseline (523.246 us; speedup 1.0000x reference)
//
#include <hip/hip_runtime.h>
#include <math.h>

#define EPS_BN 1e-5f
#define NBUK 128
#define BSHIFT 9
#define BCAP 16384
#define SCAP 14336

typedef __bf16 bf16x8 __attribute__((ext_vector_type(8)));
typedef float floatx4 __attribute__((ext_vector_type(4)));

__device__ __forceinline__ float lrelu(float x) { return x > 0.f ? x : 0.2f * x; }

__device__ __forceinline__ unsigned short f2b(float f) {
    unsigned int b = __float_as_uint(f);
    b = (b + 0x7fffu + ((b >> 16) & 1u)) >> 16;
    return (unsigned short)b;
}
__device__ __forceinline__ float b2f_lo(unsigned int u) { return __uint_as_float(u << 16); }
__device__ __forceinline__ float b2f_hi(unsigned int u) { return __uint_as_float(u & 0xffff0000u); }

__device__ __forceinline__ float sel4(float a, float b, float c, float d, int h) {
    return h < 2 ? (h == 0 ? a : b) : (h == 2 ? c : d);
}

// ---------------- edge dtype probe + workspace zeroing ----------------
__global__ void k_detect64(const int* __restrict__ ei, int* flag, int nwords,
                           int* __restrict__ gcnt, float* __restrict__ bns) {
    int lane = threadIdx.x;  // 64
    int lim = nwords < 512 ? nwords : 512;
    int zeros = 0;
    for (int i = 2 * lane + 1; i < lim; i += 128) zeros += (ei[i] == 0);
    for (int off = 32; off >= 1; off >>= 1) zeros += __shfl_xor(zeros, off, 64);
    if (lane == 0) *flag = (zeros > lim / 8) ? 1 : 0;
    for (int i = lane; i < NBUK; i += 64) gcnt[i] = 0;
    for (int i = lane; i < 768; i += 64) bns[i] = 0.f;
}

// ---------------- bucketed CSR build: bin edges + (fused) weight prep ----------------
__global__ __launch_bounds__(256) void k_bin_prep(
    const int* __restrict__ ei, const int* __restrict__ flag, int E,
    int* __restrict__ gcnt, int2* __restrict__ pairs, int binB,
    const float* __restrict__ W0, const float* __restrict__ W1,
    const float* __restrict__ W2, const float* __restrict__ as2,
    const float* __restrict__ ad2, unsigned short* __restrict__ WT0,
    unsigned short* __restrict__ WT1, unsigned short* __restrict__ WT2,
    float* __restrict__ Wt, const float* __restrict__ x,
    unsigned short* __restrict__ xb, int n4) {
    if (blockIdx.x >= binB) {
        int bid = blockIdx.x - binB;
        if (bid < 64) {
            int idx = bid * 256 + threadIdx.x;  // 16384 total
            int c = idx >> 7, k = idx & 127;
            WT0[idx] = f2b(W0[(size_t)k * 128 + c]);
        } else if (bid < 128) {
            int idx = (bid - 64) * 256 + threadIdx.x;
            int c = idx >> 7, k = idx & 127;
            WT1[idx] = f2b(W1[(size_t)k * 128 + c]);
        } else if (bid < 384) {
            int idx = (bid - 128) * 256 + threadIdx.x;  // 65536 total
            int c = idx >> 9, j = idx & 511;
            WT2[idx] = f2b(0.25f * W2[(size_t)(j & 127) * 512 + (j >> 7) * 128 + c]);
        } else if (bid < 640) {
            int wid = ((bid - 384) * 256 + threadIdx.x) >> 6;
            int lane = threadIdx.x & 63;
            if (wid < 1024) {
                int k = wid & 127, hh = (wid >> 7) & 3, isd = wid >> 9;
                const float* att = isd ? ad2 : as2;
                float v = W2[(size_t)k * 512 + hh * 128 + lane] * att[hh * 128 + lane] +
                          W2[(size_t)k * 512 + hh * 128 + 64 + lane] * att[hh * 128 + 64 + lane];
                for (int m = 32; m >= 1; m >>= 1) v += __shfl_xor(v, m, 64);
                if (lane == 0) Wt[isd * 512 + hh * 128 + k] = v;
            }
        } else {
            int i = (bid - 640) * 256 + threadIdx.x;
            if (i < n4) {
                float4 v = ((const float4*)x)[i];
                ushort4 o = make_ushort4(f2b(v.x), f2b(v.y), f2b(v.z), f2b(v.w));
                ((ushort4*)xb)[i] = o;
            }
        }
        return;
    }
    __shared__ int hist[NBUK], cnt2[NBUK], startb[NBUK], gbase[NBUK], sc[NBUK];
    __shared__ int2 stage[1024];
    int t = threadIdx.x;
    int e0 = blockIdx.x * 1024;
    int nblk = min(1024, E - e0);
    int f = *flag;
    if (t < NBUK) { hist[t] = 0; cnt2[t] = 0; }
    __syncthreads();
    int2 pr[4];
    int bb[4], m = 0;
    int idx0 = e0 + t * 4;
    if (idx0 + 4 <= E) {
        int4 s, d;
        if (f) {
            s = make_int4(ei[2 * idx0], ei[2 * idx0 + 2], ei[2 * idx0 + 4], ei[2 * idx0 + 6]);
            d = make_int4(ei[2 * (E + idx0)], ei[2 * (E + idx0) + 2],
                          ei[2 * (E + idx0) + 4], ei[2 * (E + idx0) + 6]);
        } else {
            s = *(const int4*)(ei + idx0);
            d = *(const int4*)(ei + E + idx0);
        }
        pr[0] = make_int2(s.x, d.x); pr[1] = make_int2(s.y, d.y);
        pr[2] = make_int2(s.z, d.z); pr[3] = make_int2(s.w, d.w);
        m = 4;
    } else {
        for (int i = idx0; i < E; ++i)
            pr[m++] = make_int2(f ? ei[2 * i] : ei[i], f ? ei[2 * (E + i)] : ei[E + i]);
    }
#pragma unroll
    for (int k = 0; k < 4; k++)
        if (k < m) { bb[k] = pr[k].y >> BSHIFT; atomicAdd(&hist[bb[k]], 1); }
    __syncthreads();
    if (t < NBUK) sc[t] = hist[t];
    __syncthreads();
    for (int off = 1; off < NBUK; off <<= 1) {
        int v = 0;
        if (t < NBUK && t >= off) v = sc[t - off];
        __syncthreads();
        if (t < NBUK) sc[t] += v;
        __syncthreads();
    }
    if (t < NBUK) {
        startb[t] = sc[t] - hist[t];
        gbase[t] = hist[t] ? atomicAdd(&gcnt[t], hist[t]) : 0;
    }
    __syncthreads();
#pragma unroll
    for (int k = 0; k < 4; k++)
        if (k < m) {
            int r = atomicAdd(&cnt2[bb[k]], 1);
            stage[startb[bb[k]] + r] = pr[k];
        }
    __syncthreads();
    for (int i = t; i < nblk; i += 256) {
        int2 q = stage[i];
        int b = q.y >> BSHIFT;
        pairs[(size_t)b * BCAP + gbase[b] + (i - startb[b])] = q;
    }
}

__global__ __launch_bounds__(256) void k_bdeg2(const int2* __restrict__ pairs,
                                               const int* __restrict__ gcnt,
                                               int* __restrict__ deg, int N) {
    __shared__ int hist[512];
    int t = threadIdx.x, b = blockIdx.x, d0 = b << BSHIFT;
    hist[t] = 0; hist[t + 256] = 0;
    __syncthreads();
    int cnt = gcnt[b];
    const int2* pp = pairs + (size_t)b * BCAP;
    for (int i = t; i < cnt; i += 256) atomicAdd(&hist[pp[i].y - d0], 1);
    __syncthreads();
    if (d0 + t < N) deg[d0 + t] = hist[t];
    if (d0 + t + 256 < N) deg[d0 + t + 256] = hist[t + 256];
}

__global__ void k_scan1(const int* __restrict__ deg, int* rowptr, int* bsum, int N) {
    __shared__ int lds[256];
    int t = threadIdx.x, n = blockIdx.x * 256 + t;
    int v = (n < N) ? deg[n] + 1 : 0;
    int xv = v;
    lds[t] = xv;
    __syncthreads();
    for (int off = 1; off < 256; off <<= 1) {
        int tmp = (t >= off) ? lds[t - off] : 0;
        __syncthreads();
        xv += tmp;
        lds[t] = xv;
        __syncthreads();
    }
    if (n < N) rowptr[n + 1] = xv;
    if (t == 255) bsum[blockIdx.x] = xv;
}

// scan3 computes its own exclusive prefix of bsum
__global__ void k_scan3(int* rowptr, const int* __restrict__ bsum, int N) {
    __shared__ int red[256];
    int t = threadIdx.x;
    int bid = blockIdx.x;
    int acc = 0;
    for (int k = t; k < bid; k += 256) acc += bsum[k];
    red[t] = acc;
    __syncthreads();
    for (int off = 128; off >= 1; off >>= 1) {
        if (t < off) red[t] += red[t + off];
        __syncthreads();
    }
    int pref = red[0];
    int n = bid * 256 + t;
    if (n < N) rowptr[n + 1] += pref;
    if (n == 0) rowptr[0] = 0;
}

__global__ __launch_bounds__(256) void k_bsort(const int2* __restrict__ pairs,
                                               const int* __restrict__ gcnt,
                                               const int* __restrict__ rowptr,
                                               int* __restrict__ eidx, int N) {
    __shared__ int curs[512];
    __shared__ int simg[SCAP];
    int t = threadIdx.x, b = blockIdx.x, d0 = b << BSHIFT;
    int d1 = min(d0 + 512, N);
    int seg0 = rowptr[d0], seg1 = rowptr[d1];
    int span = seg1 - seg0;
    int cnt = gcnt[b];
    const int2* pp = pairs + (size_t)b * BCAP;
    if (span <= SCAP) {
        for (int idx = t; idx < d1 - d0; idx += 256) {
            int rb = rowptr[d0 + idx], re = rowptr[d0 + idx + 1];
            curs[idx] = rb - seg0;
            simg[re - 1 - seg0] = d0 + idx;  // self loop at last slot
        }
        __syncthreads();
        for (int i = t; i < cnt; i += 256) {
            int2 q = pp[i];
            int r = atomicAdd(&curs[q.y - d0], 1);
            simg[r] = q.x;
        }
        __syncthreads();
        for (int i = t; i < span; i += 256) eidx[seg0 + i] = simg[i];
    } else {
        for (int idx = t; idx < d1 - d0; idx += 256) {
            curs[idx] = rowptr[d0 + idx];
            eidx[rowptr[d0 + idx + 1] - 1] = d0 + idx;
        }
        __syncthreads();
        for (int i = t; i < cnt; i += 256) {
            int2 q = pp[i];
            int r = atomicAdd(&curs[q.y - d0], 1);
            eidx[r] = q.x;
        }
    }
}

// ---------------- LDS fragment load ----------------
__device__ __forceinline__ bf16x8 lds_frag(const unsigned short* pp) {
    union { bf16x8 v; uint2 u2[2]; } t;
    t.u2[0] = *(const uint2*)pp;
    t.u2[1] = *(const uint2*)(pp + 4);
    return t.v;
}

// ---------------- tiled MFMA GEMM (optional fused attention scores / fused BN on A) ----
template <int K, bool BNA>
__global__ __launch_bounds__(256) void k_tgemm(const unsigned short* __restrict__ A,
                                               const float* __restrict__ Af,
                                               const float* __restrict__ bnA,
                                               const float* __restrict__ gammaA,
                                               const float* __restrict__ betaA,
                                               const unsigned short* __restrict__ WT,
                                               float* __restrict__ out,
                                               unsigned short* __restrict__ out16,
                                               const float* __restrict__ att_s,
                                               const float* __restrict__ att_d,
                                               float* __restrict__ a_s,
                                               float* __restrict__ a_d, int N) {
    __shared__ unsigned short Ast[64 * 36];
    __shared__ unsigned short Bst[128 * 36];
    __shared__ float bntab[BNA ? 512 : 1];
    const int tid = threadIdx.x;
    const int lane = tid & 63, w = tid >> 6;
    const int l16 = lane & 15, quad = lane >> 4;
    const int rowbase = blockIdx.x * 64;
    const int sar = tid >> 2, sak = tid & 3;
    const int sbc = tid >> 1, sbk = tid & 1;
    const long arow_g = min(rowbase + sar, N - 1);

    if constexpr (BNA) {
        if (tid < 128) {
            float invN = 1.f / (float)N;
            float mu = bnA[tid] * invN;
            float var = bnA[128 + tid] * invN - mu * mu;
            bntab[tid] = mu;
            bntab[128 + tid] = rsqrtf(var + EPS_BN);
            bntab[256 + tid] = gammaA[tid];
            bntab[384 + tid] = betaA[tid];
        }
        __syncthreads();
    }

    floatx4 acc[8];
#pragma unroll
    for (int c = 0; c < 8; c++) acc[c] = (floatx4){0.f, 0.f, 0.f, 0.f};

    const unsigned short* Ag = BNA ? nullptr : (A + (size_t)arow_g * K + sak * 8);
    const float* Agf = BNA ? (Af + (size_t)arow_g * 128 + sak * 8) : nullptr;
    const unsigned short* Bg = WT + (size_t)sbc * K + sbk * 8;

    auto loadA = [&](int k0) -> uint4 {
        if constexpr (BNA) {
            float4 v0 = *(const float4*)(Agf + k0);
            float4 v1 = *(const float4*)(Agf + k0 + 4);
            int c0 = sak * 8 + k0;
            unsigned short h[8];
#pragma unroll
            for (int j = 0; j < 4; j++) {
                int col = c0 + j;
                float y = ((((const float*)&v0)[j] - bntab[col]) * bntab[128 + col]) *
                              bntab[256 + col] + bntab[384 + col];
                y = y > 0.f ? y : __expf(y) - 1.f;
                h[j] = f2b(y);
            }
#pragma unroll
            for (int j = 0; j < 4; j++) {
                int col = c0 + 4 + j;
                float y = ((((const float*)&v1)[j] - bntab[col]) * bntab[128 + col]) *
                              bntab[256 + col] + bntab[384 + col];
                y = y > 0.f ? y : __expf(y) - 1.f;
                h[4 + j] = f2b(y);
            }
            uint4 r;
            r.x = (unsigned int)h[0] | ((unsigned int)h[1] << 16);
            r.y = (unsigned int)h[2] | ((unsigned int)h[3] << 16);
            r.z = (unsigned int)h[4] | ((unsigned int)h[5] << 16);
            r.w = (unsigned int)h[6] | ((unsigned int)h[7] << 16);
            return r;
        } else {
            return *(const uint4*)(Ag + k0);
        }
    };

    uint4 rA, rB0, rB1;
    rA = loadA(0);
    rB0 = *(const uint4*)(Bg);
    rB1 = *(const uint4*)(Bg + 16);

    unsigned short* Aw = Ast + sar * 36 + sak * 8;
    unsigned short* Bw0 = Bst + sbc * 36 + sbk * 8;
    unsigned short* Bw1 = Bw0 + 16;
    const unsigned short* Ar = Ast + (w * 16 + l16) * 36 + quad * 8;
    const unsigned short* Br = Bst + l16 * 36 + quad * 8;

#pragma unroll
    for (int k0 = 0; k0 < K; k0 += 32) {
        __syncthreads();
        *(uint2*)(Aw) = make_uint2(rA.x, rA.y);
        *(uint2*)(Aw + 4) = make_uint2(rA.z, rA.w);
        *(uint2*)(Bw0) = make_uint2(rB0.x, rB0.y);
        *(uint2*)(Bw0 + 4) = make_uint2(rB0.z, rB0.w);
        *(uint2*)(Bw1) = make_uint2(rB1.x, rB1.y);
        *(uint2*)(Bw1 + 4) = make_uint2(rB1.z, rB1.w);
        __syncthreads();
        if (k0 + 32 < K) {
            rA = loadA(k0 + 32);
            rB0 = *(const uint4*)(Bg + k0 + 32);
            rB1 = *(const uint4*)(Bg + k0 + 48);
        }
        bf16x8 af = lds_frag(Ar);
#pragma unroll
        for (int c = 0; c < 8; c++) {
            bf16x8 bf = lds_frag(Br + c * 16 * 36);
            acc[c] = __builtin_amdgcn_mfma_f32_16x16x32_bf16(af, bf, acc[c], 0, 0, 0);
        }
    }

    const int row00 = rowbase + w * 16 + quad * 4;
#pragma unroll
    for (int c = 0; c < 8; c++) {
#pragma unroll
        for (int r = 0; r < 4; r++) {
            int row = row00 + r;
            if (row < N) {
                if (out) out[(size_t)row * 128 + c * 16 + l16] = acc[c][r];
                if (out16) out16[(size_t)row * 128 + c * 16 + l16] = f2b(acc[c][r]);
            }
        }
    }
    if (att_s) {
        float asc[8], adc[8];
#pragma unroll
        for (int c = 0; c < 8; c++) {
            asc[c] = att_s[c * 16 + l16];
            adc[c] = att_d[c * 16 + l16];
        }
#pragma unroll
        for (int r = 0; r < 4; r++) {
            float ts[4] = {0.f, 0.f, 0.f, 0.f}, td[4] = {0.f, 0.f, 0.f, 0.f};
#pragma unroll
            for (int c = 0; c < 8; c++) {
                ts[c >> 1] += acc[c][r] * asc[c];
                td[c >> 1] += acc[c][r] * adc[c];
            }
#pragma unroll
            for (int off = 1; off < 16; off <<= 1) {
#pragma unroll
                for (int hh = 0; hh < 4; hh++) {
                    ts[hh] += __shfl_xor(ts[hh], off, 64);
                    td[hh] += __shfl_xor(td[hh], off, 64);
                }
            }
            int row = row00 + r;
            if (l16 == 0 && row < N) {
#pragma unroll
                for (int hh = 0; hh < 4; hh++) {
                    a_s[(size_t)row * 4 + hh] = ts[hh];
                    a_d[(size_t)row * 4 + hh] = td[hh];
                }
            }
        }
    }
}

// ---------------- single-dest fused softmax+accumulate, layers 0/1 (full wave) ----------------
__device__ __forceinline__ float2 facc01_one(int d, int lane, float4* pbw, int* sbw,
                                             const unsigned short* __restrict__ xp16,
                                             const float* __restrict__ a_s,
                                             const float* __restrict__ a_d,
                                             const int* __restrict__ rowptr,
                                             const int* __restrict__ eidx,
                                             const float* __restrict__ bias,
                                             float* __restrict__ out) {
    int hh = lane >> 4;
    float4 ad4 = *(const float4*)(a_d + (size_t)d * 4);
    int jb = rowptr[d], je = rowptr[d + 1], deg = je - jb;
    float a0 = 0.f, a1 = 0.f;
    float inv_h;
    if (deg <= 64) {
        int s = 0;
        float e0 = -INFINITY, e1 = -INFINITY, e2 = -INFINITY, e3 = -INFINITY;
        if (lane < deg) {
            s = eidx[jb + lane];
            float4 as4 = *(const float4*)(a_s + (size_t)s * 4);
            e0 = lrelu(as4.x + ad4.x);
            e1 = lrelu(as4.y + ad4.y);
            e2 = lrelu(as4.z + ad4.z);
            e3 = lrelu(as4.w + ad4.w);
        }
        float m0 = e0, m1 = e1, m2 = e2, m3 = e3;
        for (int off = 32; off >= 1; off >>= 1) {
            m0 = fmaxf(m0, __shfl_xor(m0, off, 64));
            m1 = fmaxf(m1, __shfl_xor(m1, off, 64));
            m2 = fmaxf(m2, __shfl_xor(m2, off, 64));
            m3 = fmaxf(m3, __shfl_xor(m3, off, 64));
        }
        float p0 = (lane < deg) ? __expf(e0 - m0) : 0.f;
        float p1 = (lane < deg) ? __expf(e1 - m1) : 0.f;
        float p2 = (lane < deg) ? __expf(e2 - m2) : 0.f;
        float p3 = (lane < deg) ? __expf(e3 - m3) : 0.f;
        float n0 = p0, n1 = p1, n2 = p2, n3 = p3;
        for (int off = 32; off >= 1; off >>= 1) {
            n0 += __shfl_xor(n0, off, 64);
            n1 += __shfl_xor(n1, off, 64);
            n2 += __shfl_xor(n2, off, 64);
            n3 += __shfl_xor(n3, off, 64);
        }
        inv_h = 1.f / (sel4(n0, n1, n2, n3, hh) + 1e-16f);
        if (lane < deg) {
            pbw[lane] = make_float4(p0, p1, p2, p3);
            sbw[lane] = s;
        }
        asm volatile("s_waitcnt lgkmcnt(0)" ::: "memory");
        __builtin_amdgcn_sched_barrier(0);
        int j = 0;
        for (; j + 4 <= deg; j += 4) {
            int s0 = __builtin_amdgcn_readfirstlane(sbw[j]);
            int s1 = __builtin_amdgcn_readfirstlane(sbw[j + 1]);
            int s2 = __builtin_amdgcn_readfirstlane(sbw[j + 2]);
            int s3 = __builtin_amdgcn_readfirstlane(sbw[j + 3]);
            float w0 = ((const float*)&pbw[j])[hh];
            float w1 = ((const float*)&pbw[j + 1])[hh];
            float w2 = ((const float*)&pbw[j + 2])[hh];
            float w3 = ((const float*)&pbw[j + 3])[hh];
            unsigned int u0 = *(const unsigned int*)(xp16 + (size_t)s0 * 128 + 2 * lane);
            unsigned int u1 = *(const unsigned int*)(xp16 + (size_t)s1 * 128 + 2 * lane);
            unsigned int u2 = *(const unsigned int*)(xp16 + (size_t)s2 * 128 + 2 * lane);
            unsigned int u3 = *(const unsigned int*)(xp16 + (size_t)s3 * 128 + 2 * lane);
            a0 += w0 * b2f_lo(u0) + w1 * b2f_lo(u1) + w2 * b2f_lo(u2) + w3 * b2f_lo(u3);
            a1 += w0 * b2f_hi(u0) + w1 * b2f_hi(u1) + w2 * b2f_hi(u2) + w3 * b2f_hi(u3);
        }
        for (; j < deg; ++j) {
            int sj = __builtin_amdgcn_readfirstlane(sbw[j]);
            float wj = ((const float*)&pbw[j])[hh];
            unsigned int u = *(const unsigned int*)(xp16 + (size_t)sj * 128 + 2 * lane);
            a0 += wj * b2f_lo(u);
            a1 += wj * b2f_hi(u);
        }
    } else {
        float m0 = -INFINITY, m1 = -INFINITY, m2 = -INFINITY, m3 = -INFINITY;
        for (int jj = jb + lane; jj < je; jj += 64) {
            int s = eidx[jj];
            float4 as4 = *(const float4*)(a_s + (size_t)s * 4);
            m0 = fmaxf(m0, lrelu(as4.x + ad4.x));
            m1 = fmaxf(m1, lrelu(as4.y + ad4.y));
            m2 = fmaxf(m2, lrelu(as4.z + ad4.z));
            m3 = fmaxf(m3, lrelu(as4.w + ad4.w));
        }
        for (int off = 32; off >= 1; off >>= 1) {
            m0 = fmaxf(m0, __shfl_xor(m0, off, 64));
            m1 = fmaxf(m1, __shfl_xor(m1, off, 64));
            m2 = fmaxf(m2, __shfl_xor(m2, off, 64));
            m3 = fmaxf(m3, __shfl_xor(m3, off, 64));
        }
        float n0 = 0.f, n1 = 0.f, n2 = 0.f, n3 = 0.f;
        for (int jj = jb + lane; jj < je; jj += 64) {
            int s = eidx[jj];
            float4 as4 = *(const float4*)(a_s + (size_t)s * 4);
            n0 += __expf(lrelu(as4.x + ad4.x) - m0);
            n1 += __expf(lrelu(as4.y + ad4.y) - m1);
            n2 += __expf(lrelu(as4.z + ad4.z) - m2);
            n3 += __expf(lrelu(as4.w + ad4.w) - m3);
        }
        for (int off = 32; off >= 1; off >>= 1) {
            n0 += __shfl_xor(n0, off, 64);
            n1 += __shfl_xor(n1, off, 64);
            n2 += __shfl_xor(n2, off, 64);
            n3 += __shfl_xor(n3, off, 64);
        }
        inv_h = 1.f / (sel4(n0, n1, n2, n3, hh) + 1e-16f);
        float m_h = sel4(m0, m1, m2, m3, hh);
        float ad_h = sel4(ad4.x, ad4.y, ad4.z, ad4.w, hh);
        for (int j = jb; j < je; ++j) {
            int s = __builtin_amdgcn_readfirstlane(eidx[j]);
            float4 as4 = *(const float4*)(a_s + (size_t)s * 4);
            float as_h = sel4(as4.x, as4.y, as4.z, as4.w, hh);
            float wj = __expf(lrelu(as_h + ad_h) - m_h);
            unsigned int u = *(const unsigned int*)(xp16 + (size_t)s * 128 + 2 * lane);
            a0 += wj * b2f_lo(u);
            a1 += wj * b2f_hi(u);
        }
    }
    float2 o = make_float2(a0 * inv_h + bias[2 * lane], a1 * inv_h + bias[2 * lane + 1]);
    *(float2*)(out + (size_t)d * 128 + 2 * lane) = o;
    return o;
}

// ---------------- FUSED softmax + accumulation + BN partials, layers 0/1 ----------------
// 2 dests per wave. Atomic-free BN stats: each thread owns cols (2*lane, 2*lane+1),
// accumulates its own outputs in registers, parks per-wave LDS partials (plain
// stores, no collisions), cross-wave reduce, one coalesced partial row per block.
__global__ __launch_bounds__(256) void k_facc01(const unsigned short* __restrict__ xp16,
                                                const float* __restrict__ a_s,
                                                const float* __restrict__ a_d,
                                                const int* __restrict__ rowptr,
                                                const int* __restrict__ eidx,
                                                const float* __restrict__ bias,
                                                float* __restrict__ out,
                                                float* __restrict__ partials, int N) {
    __shared__ float4 pb[4][64];
    __shared__ int sb[4][64];
    __shared__ float4 invb[4][2];
    __shared__ float bsl1[4][128], bsl2[4][128];
    int t = threadIdx.x;
    int w = t >> 6, lane = t & 63;
    int base = (blockIdx.x * 4 + w) * 2;
    float s1lo = 0.f, s1hi = 0.f, s2lo = 0.f, s2hi = 0.f;
    if (base < N) {
        bool have2 = (base + 1 < N);
        int half = lane >> 5, l32 = lane & 31;
        int hh = lane >> 4;
        int dh = base + (have2 ? half : 0);
        int jbh = rowptr[dh], jeh = rowptr[dh + 1];
        int degh = jeh - jbh;
        if (have2 && __all(degh <= 32)) {
            // ---- pass 1: half-wave per dest ----
            float4 ad4 = *(const float4*)(a_d + (size_t)dh * 4);
            int s = 0;
            float e0 = -INFINITY, e1 = -INFINITY, e2 = -INFINITY, e3 = -INFINITY;
            if (l32 < degh) {
                s = eidx[jbh + l32];
                float4 as4 = *(const float4*)(a_s + (size_t)s * 4);
                e0 = lrelu(as4.x + ad4.x);
                e1 = lrelu(as4.y + ad4.y);
                e2 = lrelu(as4.z + ad4.z);
                e3 = lrelu(as4.w + ad4.w);
            }
            // prefetch first 4-edge block per dest (loads overlap softmax)
            int sa0 = __builtin_amdgcn_readfirstlane(__shfl(s, 0, 64));
            int sa1 = __builtin_amdgcn_readfirstlane(__shfl(s, 1, 64));
            int sa2 = __builtin_amdgcn_readfirstlane(__shfl(s, 2, 64));
            int sa3 = __builtin_amdgcn_readfirstlane(__shfl(s, 3, 64));
            int sb0 = __builtin_amdgcn_readfirstlane(__shfl(s, 32, 64));
            int sb1 = __builtin_amdgcn_readfirstlane(__shfl(s, 33, 64));
            int sb2 = __builtin_amdgcn_readfirstlane(__shfl(s, 34, 64));
            int sb3 = __builtin_amdgcn_readfirstlane(__shfl(s, 35, 64));
            unsigned int upA0 = *(const unsigned int*)(xp16 + (size_t)sa0 * 128 + 2 * lane);
            unsigned int upA1 = *(const unsigned int*)(xp16 + (size_t)sa1 * 128 + 2 * lane);
            unsigned int upA2 = *(const unsigned int*)(xp16 + (size_t)sa2 * 128 + 2 * lane);
            unsigned int upA3 = *(const unsigned int*)(xp16 + (size_t)sa3 * 128 + 2 * lane);
            unsigned int upB0 = *(const unsigned int*)(xp16 + (size_t)sb0 * 128 + 2 * lane);
            unsigned int upB1 = *(const unsigned int*)(xp16 + (size_t)sb1 * 128 + 2 * lane);
            unsigned int upB2 = *(const unsigned int*)(xp16 + (size_t)sb2 * 128 + 2 * lane);
            unsigned int upB3 = *(const unsigned int*)(xp16 + (size_t)sb3 * 128 + 2 * lane);
            float m0 = e0, m1 = e1, m2 = e2, m3 = e3;
            for (int off = 16; off >= 1; off >>= 1) {
                m0 = fmaxf(m0, __shfl_xor(m0, off, 32));
                m1 = fmaxf(m1, __shfl_xor(m1, off, 32));
                m2 = fmaxf(m2, __shfl_xor(m2, off, 32));
                m3 = fmaxf(m3, __shfl_xor(m3, off, 32));
            }
            float p0 = (l32 < degh) ? __expf(e0 - m0) : 0.f;
            float p1 = (l32 < degh) ? __expf(e1 - m1) : 0.f;
            float p2 = (l32 < degh) ? __expf(e2 - m2) : 0.f;
            float p3 = (l32 < degh) ? __expf(e3 - m3) : 0.f;
            float n0 = p0, n1 = p1, n2 = p2, n3 = p3;
            for (int off = 16; off >= 1; off >>= 1) {
                n0 += __shfl_xor(n0, off, 32);
                n1 += __shfl_xor(n1, off, 32);
                n2 += __shfl_xor(n2, off, 32);
                n3 += __shfl_xor(n3, off, 32);
            }
            if (l32 == 0)
                invb[w][half] = make_float4(1.f / (n0 + 1e-16f), 1.f / (n1 + 1e-16f),
                                            1.f / (n2 + 1e-16f), 1.f / (n3 + 1e-16f));
            if (l32 < degh) {
                pb[w][half * 32 + l32] = make_float4(p0, p1, p2, p3);
                sb[w][half * 32 + l32] = s;
            }
            asm volatile("s_waitcnt lgkmcnt(0)" ::: "memory");
            __builtin_amdgcn_sched_barrier(0);
            int deg0 = __shfl(degh, 0, 64);
            int deg1 = __shfl(degh, 32, 64);
            // ---- pass 2: full wave, one dest at a time ----
#pragma unroll
            for (int tt = 0; tt < 2; ++tt) {
                int degt = tt ? deg1 : deg0;
                const float4* pbt = &pb[w][tt * 32];
                const int* sbt = &sb[w][tt * 32];
                float a0 = 0.f, a1 = 0.f;
                int j = 0;
                if (degt >= 4) {  // first block consumes the prefetched loads
                    float w0 = ((const float*)&pbt[0])[hh];
                    float w1 = ((const float*)&pbt[1])[hh];
                    float w2 = ((const float*)&pbt[2])[hh];
                    float w3 = ((const float*)&pbt[3])[hh];
                    unsigned int u0 = tt ? upB0 : upA0;
                    unsigned int u1 = tt ? upB1 : upA1;
                    unsigned int u2 = tt ? upB2 : upA2;
                    unsigned int u3 = tt ? upB3 : upA3;
                    a0 += w0 * b2f_lo(u0) + w1 * b2f_lo(u1) + w2 * b2f_lo(u2) + w3 * b2f_lo(u3);
                    a1 += w0 * b2f_hi(u0) + w1 * b2f_hi(u1) + w2 * b2f_hi(u2) + w3 * b2f_hi(u3);
                    j = 4;
                }
                for (; j + 4 <= degt; j += 4) {
                    int s0 = __builtin_amdgcn_readfirstlane(sbt[j]);
                    int s1 = __builtin_amdgcn_readfirstlane(sbt[j + 1]);
                    int s2 = __builtin_amdgcn_readfirstlane(sbt[j + 2]);
                    int s3 = __builtin_amdgcn_readfirstlane(sbt[j + 3]);
                    float w0 = ((const float*)&pbt[j])[hh];
                    float w1 = ((const float*)&pbt[j + 1])[hh];
                    float w2 = ((const float*)&pbt[j + 2])[hh];
                    float w3 = ((const float*)&pbt[j + 3])[hh];
                    unsigned int u0 = *(const unsigned int*)(xp16 + (size_t)s0 * 128 + 2 * lane);
                    unsigned int u1 = *(const unsigned int*)(xp16 + (size_t)s1 * 128 + 2 * lane);
                    unsigned int u2 = *(const unsigned int*)(xp16 + (size_t)s2 * 128 + 2 * lane);
                    unsigned int u3 = *(const unsigned int*)(xp16 + (size_t)s3 * 128 + 2 * lane);
                    a0 += w0 * b2f_lo(u0) + w1 * b2f_lo(u1) + w2 * b2f_lo(u2) + w3 * b2f_lo(u3);
                    a1 += w0 * b2f_hi(u0) + w1 * b2f_hi(u1) + w2 * b2f_hi(u2) + w3 * b2f_hi(u3);
                }
                for (; j < degt; ++j) {
                    int sj = __builtin_amdgcn_readfirstlane(sbt[j]);
                    float wj = ((const float*)&pbt[j])[hh];
                    unsigned int u = *(const unsigned int*)(xp16 + (size_t)sj * 128 + 2 * lane);
                    a0 += wj * b2f_lo(u);
                    a1 += wj * b2f_hi(u);
                }
                float inv = ((const float*)&invb[w][tt])[hh];
                float2 o = make_float2(a0 * inv + bias[2 * lane], a1 * inv + bias[2 * lane + 1]);
                *(float2*)(out + (size_t)(base + tt) * 128 + 2 * lane) = o;
                s1lo += o.x; s1hi += o.y;
                s2lo += o.x * o.x; s2hi += o.y * o.y;
            }
        } else {
            float2 oA = facc01_one(base, lane, pb[w], sb[w], xp16, a_s, a_d, rowptr, eidx,
                                   bias, out);
            s1lo += oA.x; s1hi += oA.y;
            s2lo += oA.x * oA.x; s2hi += oA.y * oA.y;
            if (have2) {
                float2 oB = facc01_one(base + 1, lane, pb[w], sb[w], xp16, a_s, a_d, rowptr,
                                       eidx, bias, out);
                s1lo += oB.x; s1hi += oB.y;
                s2lo += oB.x * oB.x; s2hi += oB.y * oB.y;
            }
        }
    }
    // ---- atomic-free BN partials: per-wave slots -> cross-wave reduce -> global row ----
    bsl1[w][2 * lane] = s1lo;
    bsl1[w][2 * lane + 1] = s1hi;
    bsl2[w][2 * lane] = s2lo;
    bsl2[w][2 * lane + 1] = s2hi;
    __syncthreads();
    if (t < 128) {
        float p1 = bsl1[0][t] + bsl1[1][t] + bsl1[2][t] + bsl1[3][t];
        float p2 = bsl2[0][t] + bsl2[1][t] + bsl2[2][t] + bsl2[3][t];
        partials[(size_t)blockIdx.x * 256 + t] = p1;
        partials[(size_t)blockIdx.x * 256 + 128 + t] = p2;
    }
}

// ---------------- BN partial reduce (few atomics per column) ----------------
__global__ void k_bnred(const float* __restrict__ partials, float* __restrict__ sums,
                        int nblk) {
    int c = threadIdx.x;  // 256
    float acc = 0.f;
    for (int b = blockIdx.x; b < nblk; b += gridDim.x)
        acc += partials[(size_t)b * 256 + c];
    atomicAdd(&sums[c], acc);
}

// ---------------- single-dest fused softmax+accumulate, layer 2 (full wave) ----------------
__device__ __forceinline__ void faccL2_one(int d, int lane, float4* pbw, int* sbw,
                                           const unsigned short* __restrict__ hb16,
                                           const float* __restrict__ a_s,
                                           const float* __restrict__ a_d,
                                           const int* __restrict__ rowptr,
                                           const int* __restrict__ eidx,
                                           unsigned short* __restrict__ agg16) {
    float4 ad4 = *(const float4*)(a_d + (size_t)d * 4);
    int jb = rowptr[d], je = rowptr[d + 1], deg = je - jb;
    float acc[4][2] = {{0.f, 0.f}, {0.f, 0.f}, {0.f, 0.f}, {0.f, 0.f}};
    float iv0, iv1, iv2, iv3;
    if (deg <= 64) {
        int s = 0;
        float e0 = -INFINITY, e1 = -INFINITY, e2 = -INFINITY, e3 = -INFINITY;
        if (lane < deg) {
            s = eidx[jb + lane];
            float4 as4 = *(const float4*)(a_s + (size_t)s * 4);
            e0 = lrelu(as4.x + ad4.x);
            e1 = lrelu(as4.y + ad4.y);
            e2 = lrelu(as4.z + ad4.z);
            e3 = lrelu(as4.w + ad4.w);
        }
        float m0 = e0, m1 = e1, m2 = e2, m3 = e3;
        for (int off = 32; off >= 1; off >>= 1) {
            m0 = fmaxf(m0, __shfl_xor(m0, off, 64));
            m1 = fmaxf(m1, __shfl_xor(m1, off, 64));
            m2 = fmaxf(m2, __shfl_xor(m2, off, 64));
            m3 = fmaxf(m3, __shfl_xor(m3, off, 64));
        }
        float p0 = (lane < deg) ? __expf(e0 - m0) : 0.f;
        float p1 = (lane < deg) ? __expf(e1 - m1) : 0.f;
        float p2 = (lane < deg) ? __expf(e2 - m2) : 0.f;
        float p3 = (lane < deg) ? __expf(e3 - m3) : 0.f;
        float n0 = p0, n1 = p1, n2 = p2, n3 = p3;
        for (int off = 32; off >= 1; off >>= 1) {
            n0 += __shfl_xor(n0, off, 64);
            n1 += __shfl_xor(n1, off, 64);
            n2 += __shfl_xor(n2, off, 64);
            n3 += __shfl_xor(n3, off, 64);
        }
        iv0 = 1.f / (n0 + 1e-16f);
        iv1 = 1.f / (n1 + 1e-16f);
        iv2 = 1.f / (n2 + 1e-16f);
        iv3 = 1.f / (n3 + 1e-16f);
        if (lane < deg) {
            pbw[lane] = make_float4(p0, p1, p2, p3);
            sbw[lane] = s;
        }
        asm volatile("s_waitcnt lgkmcnt(0)" ::: "memory");
        __builtin_amdgcn_sched_barrier(0);
        int j = 0;
        for (; j + 4 <= deg; j += 4) {
            int s0 = __builtin_amdgcn_readfirstlane(sbw[j]);
            int s1 = __builtin_amdgcn_readfirstlane(sbw[j + 1]);
            int s2 = __builtin_amdgcn_readfirstlane(sbw[j + 2]);
            int s3 = __builtin_amdgcn_readfirstlane(sbw[j + 3]);
            float4 w0 = pbw[j], w1 = pbw[j + 1], w2 = pbw[j + 2], w3 = pbw[j + 3];
            unsigned int u0 = *(const unsigned int*)(hb16 + (size_t)s0 * 128 + 2 * lane);
            unsigned int u1 = *(const unsigned int*)(hb16 + (size_t)s1 * 128 + 2 * lane);
            unsigned int u2 = *(const unsigned int*)(hb16 + (size_t)s2 * 128 + 2 * lane);
            unsigned int u3 = *(const unsigned int*)(hb16 + (size_t)s3 * 128 + 2 * lane);
            float lo0 = b2f_lo(u0), hi0 = b2f_hi(u0);
            float lo1 = b2f_lo(u1), hi1 = b2f_hi(u1);
            float lo2 = b2f_lo(u2), hi2 = b2f_hi(u2);
            float lo3 = b2f_lo(u3), hi3 = b2f_hi(u3);
#pragma unroll
            for (int hh = 0; hh < 4; hh++) {
                acc[hh][0] += ((const float*)&w0)[hh] * lo0 + ((const float*)&w1)[hh] * lo1 +
                              ((const float*)&w2)[hh] * lo2 + ((const float*)&w3)[hh] * lo3;
                acc[hh][1] += ((const float*)&w0)[hh] * hi0 + ((const float*)&w1)[hh] * hi1 +
                              ((const float*)&w2)[hh] * hi2 + ((const float*)&w3)[hh] * hi3;
            }
        }
        for (; j < deg; ++j) {
            int sj = __builtin_amdgcn_readfirstlane(sbw[j]);
            float4 wj = pbw[j];
            unsigned int u = *(const unsigned int*)(hb16 + (size_t)sj * 128 + 2 * lane);
            float lo = b2f_lo(u), hi = b2f_hi(u);
#pragma unroll
            for (int hh = 0; hh < 4; hh++) {
                acc[hh][0] += ((const float*)&wj)[hh] * lo;
                acc[hh][1] += ((const float*)&wj)[hh] * hi;
            }
        }
    } else {
        float m0 = -INFINITY, m1 = -INFINITY, m2 = -INFINITY, m3 = -INFINITY;
        for (int jj = jb + lane; jj < je; jj += 64) {
            int s = eidx[jj];
            float4 as4 = *(const float4*)(a_s + (size_t)s * 4);
            m0 = fmaxf(m0, lrelu(as4.x + ad4.x));
            m1 = fmaxf(m1, lrelu(as4.y + ad4.y));
            m2 = fmaxf(m2, lrelu(as4.z + ad4.z));
            m3 = fmaxf(m3, lrelu(as4.w + ad4.w));
        }
        for (int off = 32; off >= 1; off >>= 1) {
            m0 = fmaxf(m0, __shfl_xor(m0, off, 64));
            m1 = fmaxf(m1, __shfl_xor(m1, off, 64));
            m2 = fmaxf(m2, __shfl_xor(m2, off, 64));
            m3 = fmaxf(m3, __shfl_xor(m3, off, 64));
        }
        float n0 = 0.f, n1 = 0.f, n2 = 0.f, n3 = 0.f;
        for (int jj = jb + lane; jj < je; jj += 64) {
            int s = eidx[jj];
            float4 as4 = *(const float4*)(a_s + (size_t)s * 4);
            n0 += __expf(lrelu(as4.x + ad4.x) - m0);
            n1 += __expf(lrelu(as4.y + ad4.y) - m1);
            n2 += __expf(lrelu(as4.z + ad4.z) - m2);
            n3 += __expf(lrelu(as4.w + ad4.w) - m3);
        }
        for (int off = 32; off >= 1; off >>= 1) {
            n0 += __shfl_xor(n0, off, 64);
            n1 += __shfl_xor(n1, off, 64);
            n2 += __shfl_xor(n2, off, 64);
            n3 += __shfl_xor(n3, off, 64);
        }
        iv0 = 1.f / (n0 + 1e-16f);
        iv1 = 1.f / (n1 + 1e-16f);
        iv2 = 1.f / (n2 + 1e-16f);
        iv3 = 1.f / (n3 + 1e-16f);
        for (int j = jb; j < je; ++j) {
            int s = __builtin_amdgcn_readfirstlane(eidx[j]);
            float4 as4 = *(const float4*)(a_s + (size_t)s * 4);
            float w0 = __expf(lrelu(as4.x + ad4.x) - m0);
            float w1 = __expf(lrelu(as4.y + ad4.y) - m1);
            float w2 = __expf(lrelu(as4.z + ad4.z) - m2);
            float w3 = __expf(lrelu(as4.w + ad4.w) - m3);
            unsigned int u = *(const unsigned int*)(hb16 + (size_t)s * 128 + 2 * lane);
            float lo = b2f_lo(u), hi = b2f_hi(u);
            acc[0][0] += w0 * lo; acc[0][1] += w0 * hi;
            acc[1][0] += w1 * lo; acc[1][1] += w1 * hi;
            acc[2][0] += w2 * lo; acc[2][1] += w2 * hi;
            acc[3][0] += w3 * lo; acc[3][1] += w3 * hi;
        }
    }
    float iv[4] = {iv0, iv1, iv2, iv3};
#pragma unroll
    for (int hh = 0; hh < 4; hh++) {
        ushort2 o = make_ushort2(f2b(acc[hh][0] * iv[hh]), f2b(acc[hh][1] * iv[hh]));
        *(ushort2*)(agg16 + (size_t)d * 512 + hh * 128 + 2 * lane) = o;
    }
}

// ---------------- FUSED softmax + accumulation, layer 2 (2 dests per wave) ----------------
__global__ __launch_bounds__(256) void k_faccL2(const unsigned short* __restrict__ hb16,
                                                const float* __restrict__ a_s,
                                                const float* __restrict__ a_d,
                                                const int* __restrict__ rowptr,
                                                const int* __restrict__ eidx,
                                                unsigned short* __restrict__ agg16, int N) {
    __shared__ float4 pb[4][64];
    __shared__ int sb[4][64];
    __shared__ float4 invb[4][2];
    int w = threadIdx.x >> 6, lane = threadIdx.x & 63;
    int base = (blockIdx.x * 4 + w) * 2;
    if (base >= N) return;
    bool have2 = (base + 1 < N);
    int half = lane >> 5, l32 = lane & 31;
    int dh = base + (have2 ? half : 0);
    int jbh = rowptr[dh], jeh = rowptr[dh + 1];
    int degh = jeh - jbh;
    if (have2 && __all(degh <= 32)) {
        // ---- pass 1: half-wave per dest ----
        float4 ad4 = *(const float4*)(a_d + (size_t)dh * 4);
        int s = 0;
        float e0 = -INFINITY, e1 = -INFINITY, e2 = -INFINITY, e3 = -INFINITY;
        if (l32 < degh) {
            s = eidx[jbh + l32];
            float4 as4 = *(const float4*)(a_s + (size_t)s * 4);
            e0 = lrelu(as4.x + ad4.x);
            e1 = lrelu(as4.y + ad4.y);
            e2 = lrelu(as4.z + ad4.z);
            e3 = lrelu(as4.w + ad4.w);
        }
        // prefetch first 4-edge block per dest
        int sa0 = __builtin_amdgcn_readfirstlane(__shfl(s, 0, 64));
        int sa1 = __builtin_amdgcn_readfirstlane(__shfl(s, 1, 64));
        int sa2 = __builtin_amdgcn_readfirstlane(__shfl(s, 2, 64));
        int sa3 = __builtin_amdgcn_readfirstlane(__shfl(s, 3, 64));
        int sb0 = __builtin_amdgcn_readfirstlane(__shfl(s, 32, 64));
        int sb1 = __builtin_amdgcn_readfirstlane(__shfl(s, 33, 64));
        int sb2 = __builtin_amdgcn_readfirstlane(__shfl(s, 34, 64));
        int sb3 = __builtin_amdgcn_readfirstlane(__shfl(s, 35, 64));
        unsigned int upA0 = *(const unsigned int*)(hb16 + (size_t)sa0 * 128 + 2 * lane);
        unsigned int upA1 = *(const unsigned int*)(hb16 + (size_t)sa1 * 128 + 2 * lane);
        unsigned int upA2 = *(const unsigned int*)(hb16 + (size_t)sa2 * 128 + 2 * lane);
        unsigned int upA3 = *(const unsigned int*)(hb16 + (size_t)sa3 * 128 + 2 * lane);
        unsigned int upB0 = *(const unsigned int*)(hb16 + (size_t)sb0 * 128 + 2 * lane);
        unsigned int upB1 = *(const unsigned int*)(hb16 + (size_t)sb1 * 128 + 2 * lane);
        unsigned int upB2 = *(const unsigned int*)(hb16 + (size_t)sb2 * 128 + 2 * lane);
        unsigned int upB3 = *(const unsigned int*)(hb16 + (size_t)sb3 * 128 + 2 * lane);
        float m0 = e0, m1 = e1, m2 = e2, m3 = e3;
        for (int off = 16; off >= 1; off >>= 1) {
            m0 = fmaxf(m0, __shfl_xor(m0, off, 32));
            m1 = fmaxf(m1, __shfl_xor(m1, off, 32));
            m2 = fmaxf(m2, __shfl_xor(m2, off, 32));
            m3 = fmaxf(m3, __shfl_xor(m3, off, 32));
        }
        float p0 = (l32 < degh) ? __expf(e0 - m0) : 0.f;
        float p1 = (l32 < degh) ? __expf(e1 - m1) : 0.f;
        float p2 = (l32 < degh) ? __expf(e2 - m2) : 0.f;
        float p3 = (l32 < degh) ? __expf(e3 - m3) : 0.f;
        float n0 = p0, n1 = p1, n2 = p2, n3 = p3;
        for (int off = 16; off >= 1; off >>= 1) {
            n0 += __shfl_xor(n0, off, 32);
            n1 += __shfl_xor(n1, off, 32);
            n2 += __shfl_xor(n2, off, 32);
            n3 += __shfl_xor(n3, off, 32);
        }
        if (l32 == 0)
            invb[w][half] = make_float4(1.f / (n0 + 1e-16f), 1.f / (n1 + 1e-16f),
                                        1.f / (n2 + 1e-16f), 1.f / (n3 + 1e-16f));
        if (l32 < degh) {
            pb[w][half * 32 + l32] = make_float4(p0, p1, p2, p3);
            sb[w][half * 32 + l32] = s;
        }
        asm volatile("s_waitcnt lgkmcnt(0)" ::: "memory");
        __builtin_amdgcn_sched_barrier(0);
        int deg0 = __shfl(degh, 0, 64);
        int deg1 = __shfl(degh, 32, 64);
        // ---- pass 2: full wave, one dest at a time ----
#pragma unroll
        for (int t = 0; t < 2; ++t) {
            int degt = t ? deg1 : deg0;
            const float4* pbt = &pb[w][t * 32];
            const int* sbt = &sb[w][t * 32];
            float acc[4][2] = {{0.f, 0.f}, {0.f, 0.f}, {0.f, 0.f}, {0.f, 0.f}};
            int j = 0;
            if (degt >= 4) {  // first block consumes the prefetched loads
                float4 w0 = pbt[0], w1 = pbt[1], w2 = pbt[2], w3 = pbt[3];
                unsigned int u0 = t ? upB0 : upA0;
                unsigned int u1 = t ? upB1 : upA1;
                unsigned int u2 = t ? upB2 : upA2;
                unsigned int u3 = t ? upB3 : upA3;
                float lo0 = b2f_lo(u0), hi0 = b2f_hi(u0);
                float lo1 = b2f_lo(u1), hi1 = b2f_hi(u1);
                float lo2 = b2f_lo(u2), hi2 = b2f_hi(u2);
                float lo3 = b2f_lo(u3), hi3 = b2f_hi(u3);
#pragma unroll
                for (int hh = 0; hh < 4; hh++) {
                    acc[hh][0] += ((const float*)&w0)[hh] * lo0 + ((const float*)&w1)[hh] * lo1 +
                                  ((const float*)&w2)[hh] * lo2 + ((const float*)&w3)[hh] * lo3;
                    acc[hh][1] += ((const float*)&w0)[hh] * hi0 + ((const float*)&w1)[hh] * hi1 +
                                  ((const float*)&w2)[hh] * hi2 + ((const float*)&w3)[hh] * hi3;
                }
                j = 4;
            }
            for (; j + 4 <= degt; j += 4) {
                int s0 = __builtin_amdgcn_readfirstlane(sbt[j]);
                int s1 = __builtin_amdgcn_readfirstlane(sbt[j + 1]);
                int s2 = __builtin_amdgcn_readfirstlane(sbt[j + 2]);
                int s3 = __builtin_amdgcn_readfirstlane(sbt[j + 3]);
                float4 w0 = pbt[j], w1 = pbt[j + 1], w2 = pbt[j + 2], w3 = pbt[j + 3];
                unsigned int u0 = *(const unsigned int*)(hb16 + (size_t)s0 * 128 + 2 * lane);
                unsigned int u1 = *(const unsigned int*)(hb16 + (size_t)s1 * 128 + 2 * lane);
                unsigned int u2 = *(const unsigned int*)(hb16 + (size_t)s2 * 128 + 2 * lane);
                unsigned int u3 = *(const unsigned int*)(hb16 + (size_t)s3 * 128 + 2 * lane);
                float lo0 = b2f_lo(u0), hi0 = b2f_hi(u0);
                float lo1 = b2f_lo(u1), hi1 = b2f_hi(u1);
                float lo2 = b2f_lo(u2), hi2 = b2f_hi(u2);
                float lo3 = b2f_lo(u3), hi3 = b2f_hi(u3);
#pragma unroll
                for (int hh = 0; hh < 4; hh++) {
                    acc[hh][0] += ((const float*)&w0)[hh] * lo0 + ((const float*)&w1)[hh] * lo1 +
                                  ((const float*)&w2)[hh] * lo2 + ((const float*)&w3)[hh] * lo3;
                    acc[hh][1] += ((const float*)&w0)[hh] * hi0 + ((const float*)&w1)[hh] * hi1 +
                                  ((const float*)&w2)[hh] * hi2 + ((const float*)&w3)[hh] * hi3;
                }
            }
            for (; j < degt; ++j) {
                int sj = __builtin_amdgcn_readfirstlane(sbt[j]);
                float4 wj = pbt[j];
                unsigned int u = *(const unsigned int*)(hb16 + (size_t)sj * 128 + 2 * lane);
                float lo = b2f_lo(u), hi = b2f_hi(u);
#pragma unroll
                for (int hh = 0; hh < 4; hh++) {
                    acc[hh][0] += ((const float*)&wj)[hh] * lo;
                    acc[hh][1] += ((const float*)&wj)[hh] * hi;
                }
            }
            float4 ivv = invb[w][t];
            const float* iv = (const float*)&ivv;
#pragma unroll
            for (int hh = 0; hh < 4; hh++) {
                ushort2 o = make_ushort2(f2b(acc[hh][0] * iv[hh]), f2b(acc[hh][1] * iv[hh]));
                *(ushort2*)(agg16 + (size_t)(base + t) * 512 + hh * 128 + 2 * lane) = o;
            }
        }
    } else {
        faccL2_one(base, lane, pb[w], sb[w], hb16, a_s, a_d, rowptr, eidx, agg16);
        if (have2)
            faccL2_one(base + 1, lane, pb[w], sb[w], hb16, a_s, a_d, rowptr, eidx, agg16);
    }
}

// ---------------- batch norm (layer 2 only) ----------------
__global__ void k_bnstats(const float* __restrict__ x, float* __restrict__ sums, int N) {
    int col = threadIdx.x & 127, half = threadIdx.x >> 7;
    float s1 = 0.f, s2 = 0.f;
    for (int r = blockIdx.x * 2 + half; r < N; r += gridDim.x * 2) {
        float v = x[(size_t)r * 128 + col];
        s1 += v;
        s2 += v * v;
    }
    atomicAdd(&sums[col], s1);
    atomicAdd(&sums[128 + col], s2);
}

__global__ void k_bnapply(float* __restrict__ x, unsigned short* __restrict__ out16,
                          const float* __restrict__ sums, const float* __restrict__ gamma,
                          const float* __restrict__ beta, int N, int elu, int writex) {
    int idx = blockIdx.x * blockDim.x + threadIdx.x;
    if (idx >= N * 32) return;
    float4 v = ((float4*)x)[idx];
    int colb = (idx & 31) * 4;
    float invN = 1.f / (float)N;
#pragma unroll
    for (int j = 0; j < 4; j++) {
        int col = colb + j;
        float mu = sums[col] * invN;
        float var = sums[128 + col] * invN - mu * mu;
        float y = (((float*)&v)[j] - mu) * rsqrtf(var + EPS_BN) * gamma[col] + beta[col];
        if (elu) y = y > 0.f ? y : __expf(y) - 1.f;
        ((float*)&v)[j] = y;
    }
    if (writex) ((float4*)x)[idx] = v;
    if (out16) {
        ushort4 o = make_ushort4(f2b(v.x), f2b(v.y), f2b(v.z), f2b(v.w));
        ((ushort4*)out16)[idx] = o;
    }
}

// ---------------- fused BN+ELU+bf16 + layer-2 attention scores (layer 1 only) ----------------
__global__ __launch_bounds__(256) void k_bnapply_att(const float* __restrict__ x,
                                                     unsigned short* __restrict__ out16,
                                                     const float* __restrict__ sums,
                                                     const float* __restrict__ gamma,
                                                     const float* __restrict__ beta,
                                                     const float* __restrict__ Wt,
                                                     float* __restrict__ a_s,
                                                     float* __restrict__ a_d, int N) {
    int wid = (blockIdx.x * blockDim.x + threadIdx.x) >> 6;
    int lane = threadIdx.x & 63;
    if (wid >= N) return;
    float invN = 1.f / (float)N;
    int c0 = lane, c1 = 64 + lane;
    float v0 = x[(size_t)wid * 128 + c0];
    float v1 = x[(size_t)wid * 128 + c1];
    float mu0 = sums[c0] * invN;
    float var0 = sums[128 + c0] * invN - mu0 * mu0;
    float y0 = (v0 - mu0) * rsqrtf(var0 + EPS_BN) * gamma[c0] + beta[c0];
    float mu1 = sums[c1] * invN;
    float var1 = sums[128 + c1] * invN - mu1 * mu1;
    float y1 = (v1 - mu1) * rsqrtf(var1 + EPS_BN) * gamma[c1] + beta[c1];
    y0 = y0 > 0.f ? y0 : __expf(y0) - 1.f;
    y1 = y1 > 0.f ? y1 : __expf(y1) - 1.f;
    out16[(size_t)wid * 128 + c0] = f2b(y0);
    out16[(size_t)wid * 128 + c1] = f2b(y1);
    float ts[4], td[4];
#pragma unroll
    for (int hh = 0; hh < 4; hh++) {
        ts[hh] = y0 * Wt[hh * 128 + lane] + y1 * Wt[hh * 128 + 64 + lane];
        td[hh] = y0 * Wt[512 + hh * 128 + lane] + y1 * Wt[512 + hh * 128 + 64 + lane];
    }
    for (int m = 32; m >= 1; m >>= 1) {
#pragma unroll
        for (int hh = 0; hh < 4; hh++) {
            ts[hh] += __shfl_xor(ts[hh], m, 64);
            td[hh] += __shfl_xor(td[hh], m, 64);
        }
    }
    if (lane == 0) {
#pragma unroll
        for (int hh = 0; hh < 4; hh++) {
            a_s[wid * 4 + hh] = ts[hh];
            a_d[wid * 4 + hh] = td[hh];
        }
    }
}

// ---------------- launch ----------------
extern "C" void kernel_launch(void* const* d_in, const int* in_sizes, int n_in,
                              void* d_out, int out_size, void* d_ws, size_t ws_size,
                              hipStream_t stream) {
    const float* x = (const float*)d_in[0];
    const int* ei_raw = (const int*)d_in[1];
    const float* W0 = (const float*)d_in[2];
    const float* as0 = (const float*)d_in[3];
    const float* ad0 = (const float*)d_in[4];
    const float* b0 = (const float*)d_in[5];
    const float* g0 = (const float*)d_in[6];
    const float* be0 = (const float*)d_in[7];
    const float* W1 = (const float*)d_in[8];
    const float* as1 = (const float*)d_in[9];
    const float* ad1 = (const float*)d_in[10];
    const float* b1 = (const float*)d_in[11];
    const float* g1 = (const float*)d_in[12];
    const float* be1 = (const float*)d_in[13];
    const float* W2 = (const float*)d_in[14];
    const float* as2 = (const float*)d_in[15];
    const float* ad2 = (const float*)d_in[16];
    const float* g2v = (const float*)d_in[18];
    const float* be2 = (const float*)d_in[19];

    const int N = in_sizes[0] / 128;
    const int E = in_sizes[1] / 2;
    const int gw2 = (N + 7) / 8;

    // workspace carve (256B aligned)
    char* p = (char*)d_ws;
    auto alloc = [&](size_t bytes) {
        void* r = (void*)p;
        p += (bytes + 255) & ~(size_t)255;
        return r;
    };
    float* hbuf = (float*)alloc((size_t)N * 128 * 4);
    unsigned short* xb = (unsigned short*)alloc((size_t)N * 128 * 2);
    unsigned short* xp16 = (unsigned short*)alloc((size_t)N * 128 * 2);
    unsigned short* hb16 = (unsigned short*)alloc((size_t)N * 128 * 2);
    unsigned short* agg16 = (unsigned short*)alloc((size_t)N * 512 * 2);
    float* As = (float*)alloc((size_t)N * 4 * 4);
    float* Ad = (float*)alloc((size_t)N * 4 * 4);
    int* deg = (int*)alloc((size_t)N * 4);
    int* rowptr = (int*)alloc((size_t)(N + 1) * 4);
    int* bsum = (int*)alloc(1024);
    int* eidx = (int*)alloc((size_t)(E + N) * 4);
    float* bns = (float*)alloc(768 * 4);  // 3 slots of 256
    int* flag = (int*)alloc(256);
    float* Wt = (float*)alloc(1024 * 4);
    unsigned short* WT0 = (unsigned short*)alloc((size_t)128 * 128 * 2);
    unsigned short* WT1 = (unsigned short*)alloc((size_t)128 * 128 * 2);
    unsigned short* WT2 = (unsigned short*)alloc((size_t)128 * 512 * 2);
    float* partials = (float*)alloc((size_t)gw2 * 256 * 4);
    int2* pairs = (int2*)alloc((size_t)NBUK * BCAP * 8);
    int* gcnt = (int*)alloc(NBUK * 4);
    if ((size_t)(p - (char*)d_ws) > ws_size) return;

    const int nb = (N + 255) / 256;
    const int gw = (N + 3) / 4;
    const int gt = (N + 63) / 64;
    const int nbuk_used = (N + (1 << BSHIFT) - 1) >> BSHIFT;
    const int binB = (E + 1023) / 1024;
    const int prepB = 640 + (N * 32 + 255) / 256;

    // --- CSR build (bucketed, LDS-sorted); detect zeroes gcnt + bns; prep fused into bin ---
    k_detect64<<<1, 64, 0, stream>>>(ei_raw, flag, 2 * E, gcnt, bns);
    k_bin_prep<<<binB + prepB, 256, 0, stream>>>(ei_raw, flag, E, gcnt, pairs, binB, W0, W1,
                                                 W2, as2, ad2, WT0, WT1, WT2, Wt, x, xb,
                                                 N * 32);
    k_bdeg2<<<nbuk_used, 256, 0, stream>>>(pairs, gcnt, deg, N);
    k_scan1<<<nb, 256, 0, stream>>>(deg, rowptr, bsum, N);
    k_scan3<<<nb, 256, 0, stream>>>(rowptr, bsum, N);
    k_bsort<<<nbuk_used, 256, 0, stream>>>(pairs, gcnt, rowptr, eidx, N);

    // --- layer 0 (GEMM fuses attention scores; softmax + BN partials fused into accumulate) ---
    k_tgemm<128, false><<<gt, 256, 0, stream>>>(xb, (const float*)nullptr,
                                                (const float*)nullptr, (const float*)nullptr,
                                                (const float*)nullptr, WT0, (float*)nullptr,
                                                xp16, as0, ad0, As, Ad, N);
    k_facc01<<<gw2, 256, 0, stream>>>(xp16, As, Ad, rowptr, eidx, b0, hbuf, partials, N);
    k_bnred<<<32, 256, 0, stream>>>(partials, bns, gw2);
    // L0 BN+ELU+cast fused into L1 GEMM A-load (hb16 round-trip removed)

    // --- layer 1 (A = BN(hbuf) inline; BN+ELU fused with layer-2 attention scores) ---
    k_tgemm<128, true><<<gt, 256, 0, stream>>>((const unsigned short*)nullptr, hbuf, bns, g0,
                                               be0, WT1, (float*)nullptr, xp16, as1, ad1, As,
                                               Ad, N);
    k_facc01<<<gw2, 256, 0, stream>>>(xp16, As, Ad, rowptr, eidx, b1, hbuf, partials, N);
    k_bnred<<<32, 256, 0, stream>>>(partials, bns + 256, gw2);
    k_bnapply_att<<<gw, 256, 0, stream>>>(hbuf, hb16, bns + 256, g1, be1, Wt, As, Ad, N);

    // --- layer 2 ---
    float* outf = (float*)d_out;
    k_faccL2<<<gw2, 256, 0, stream>>>(hb16, As, Ad, rowptr, eidx, agg16, N);
    k_tgemm<512, false><<<gt, 256, 0, stream>>>(agg16, (const float*)nullptr,
                                                (const float*)nullptr, (const float*)nullptr,
                                                (const float*)nullptr, WT2, outf,
                                                (unsigned short*)nullptr, (const float*)nullptr,
                                                (const float*)nullptr, (float*)nullptr,
                                                (float*)nullptr, N);
    k_bnstats<<<256, 256, 0, stream>>>(outf, bns + 512, N);
    k_bnapply<<<(N * 32 + 255) / 256, 256, 0, stream>>>(outf, (unsigned short*)nullptr,
                                                        bns + 512, g2v, be2, N, 0, 1);
}

// Round 13
// 430.612 us; speedup vs baseline: 1.2151x; 1.2151x over previous
//
#include <hip/hip_runtime.h>
#include <math.h>

#define EPS_BN 1e-5f
#define NBUK 128
#define BSHIFT 9
#define BCAP 16384
#define SCAP 14336

typedef __bf16 bf16x8 __attribute__((ext_vector_type(8)));
typedef float floatx4 __attribute__((ext_vector_type(4)));

__device__ __forceinline__ float lrelu(float x) { return x > 0.f ? x : 0.2f * x; }

__device__ __forceinline__ unsigned short f2b(float f) {
    unsigned int b = __float_as_uint(f);
    b = (b + 0x7fffu + ((b >> 16) & 1u)) >> 16;
    return (unsigned short)b;
}
__device__ __forceinline__ float b2f_lo(unsigned int u) { return __uint_as_float(u << 16); }
__device__ __forceinline__ float b2f_hi(unsigned int u) { return __uint_as_float(u & 0xffff0000u); }

__device__ __forceinline__ float sel4(float a, float b, float c, float d, int h) {
    return h < 2 ? (h == 0 ? a : b) : (h == 2 ? c : d);
}

// ---------------- edge dtype probe + workspace zeroing ----------------
__global__ void k_detect64(const int* __restrict__ ei, int* flag, int nwords,
                           int* __restrict__ gcnt, float* __restrict__ bns) {
    int lane = threadIdx.x;  // 64
    int lim = nwords < 512 ? nwords : 512;
    int zeros = 0;
    for (int i = 2 * lane + 1; i < lim; i += 128) zeros += (ei[i] == 0);
    for (int off = 32; off >= 1; off >>= 1) zeros += __shfl_xor(zeros, off, 64);
    if (lane == 0) *flag = (zeros > lim / 8) ? 1 : 0;
    for (int i = lane; i < NBUK; i += 64) gcnt[i] = 0;
    for (int i = lane; i < 768; i += 64) bns[i] = 0.f;
}

// ---------------- bucketed CSR build: bin edges + (fused) weight prep ----------------
__global__ __launch_bounds__(256) void k_bin_prep(
    const int* __restrict__ ei, const int* __restrict__ flag, int E,
    int* __restrict__ gcnt, int2* __restrict__ pairs, int binB,
    const float* __restrict__ W0, const float* __restrict__ W1,
    const float* __restrict__ W2, const float* __restrict__ as2,
    const float* __restrict__ ad2, unsigned short* __restrict__ WT0,
    unsigned short* __restrict__ WT1, unsigned short* __restrict__ WT2,
    float* __restrict__ Wt, const float* __restrict__ x,
    unsigned short* __restrict__ xb, int n4) {
    if (blockIdx.x >= binB) {
        int bid = blockIdx.x - binB;
        if (bid < 64) {
            int idx = bid * 256 + threadIdx.x;  // 16384 total
            int c = idx >> 7, k = idx & 127;
            WT0[idx] = f2b(W0[(size_t)k * 128 + c]);
        } else if (bid < 128) {
            int idx = (bid - 64) * 256 + threadIdx.x;
            int c = idx >> 7, k = idx & 127;
            WT1[idx] = f2b(W1[(size_t)k * 128 + c]);
        } else if (bid < 384) {
            int idx = (bid - 128) * 256 + threadIdx.x;  // 65536 total
            int c = idx >> 9, j = idx & 511;
            WT2[idx] = f2b(0.25f * W2[(size_t)(j & 127) * 512 + (j >> 7) * 128 + c]);
        } else if (bid < 640) {
            int wid = ((bid - 384) * 256 + threadIdx.x) >> 6;
            int lane = threadIdx.x & 63;
            if (wid < 1024) {
                int k = wid & 127, hh = (wid >> 7) & 3, isd = wid >> 9;
                const float* att = isd ? ad2 : as2;
                float v = W2[(size_t)k * 512 + hh * 128 + lane] * att[hh * 128 + lane] +
                          W2[(size_t)k * 512 + hh * 128 + 64 + lane] * att[hh * 128 + 64 + lane];
                for (int m = 32; m >= 1; m >>= 1) v += __shfl_xor(v, m, 64);
                if (lane == 0) Wt[isd * 512 + hh * 128 + k] = v;
            }
        } else {
            int i = (bid - 640) * 256 + threadIdx.x;
            if (i < n4) {
                float4 v = ((const float4*)x)[i];
                ushort4 o = make_ushort4(f2b(v.x), f2b(v.y), f2b(v.z), f2b(v.w));
                ((ushort4*)xb)[i] = o;
            }
        }
        return;
    }
    __shared__ int hist[NBUK], cnt2[NBUK], startb[NBUK], gbase[NBUK], sc[NBUK];
    __shared__ int2 stage[1024];
    int t = threadIdx.x;
    int e0 = blockIdx.x * 1024;
    int nblk = min(1024, E - e0);
    int f = *flag;
    if (t < NBUK) { hist[t] = 0; cnt2[t] = 0; }
    __syncthreads();
    int2 pr[4];
    int bb[4], m = 0;
    int idx0 = e0 + t * 4;
    if (idx0 + 4 <= E) {
        int4 s, d;
        if (f) {
            s = make_int4(ei[2 * idx0], ei[2 * idx0 + 2], ei[2 * idx0 + 4], ei[2 * idx0 + 6]);
            d = make_int4(ei[2 * (E + idx0)], ei[2 * (E + idx0) + 2],
                          ei[2 * (E + idx0) + 4], ei[2 * (E + idx0) + 6]);
        } else {
            s = *(const int4*)(ei + idx0);
            d = *(const int4*)(ei + E + idx0);
        }
        pr[0] = make_int2(s.x, d.x); pr[1] = make_int2(s.y, d.y);
        pr[2] = make_int2(s.z, d.z); pr[3] = make_int2(s.w, d.w);
        m = 4;
    } else {
        for (int i = idx0; i < E; ++i)
            pr[m++] = make_int2(f ? ei[2 * i] : ei[i], f ? ei[2 * (E + i)] : ei[E + i]);
    }
#pragma unroll
    for (int k = 0; k < 4; k++)
        if (k < m) { bb[k] = pr[k].y >> BSHIFT; atomicAdd(&hist[bb[k]], 1); }
    __syncthreads();
    if (t < NBUK) sc[t] = hist[t];
    __syncthreads();
    for (int off = 1; off < NBUK; off <<= 1) {
        int v = 0;
        if (t < NBUK && t >= off) v = sc[t - off];
        __syncthreads();
        if (t < NBUK) sc[t] += v;
        __syncthreads();
    }
    if (t < NBUK) {
        startb[t] = sc[t] - hist[t];
        gbase[t] = hist[t] ? atomicAdd(&gcnt[t], hist[t]) : 0;
    }
    __syncthreads();
#pragma unroll
    for (int k = 0; k < 4; k++)
        if (k < m) {
            int r = atomicAdd(&cnt2[bb[k]], 1);
            stage[startb[bb[k]] + r] = pr[k];
        }
    __syncthreads();
    for (int i = t; i < nblk; i += 256) {
        int2 q = stage[i];
        int b = q.y >> BSHIFT;
        pairs[(size_t)b * BCAP + gbase[b] + (i - startb[b])] = q;
    }
}

__global__ __launch_bounds__(256) void k_bdeg2(const int2* __restrict__ pairs,
                                               const int* __restrict__ gcnt,
                                               int* __restrict__ deg, int N) {
    __shared__ int hist[512];
    int t = threadIdx.x, b = blockIdx.x, d0 = b << BSHIFT;
    hist[t] = 0; hist[t + 256] = 0;
    __syncthreads();
    int cnt = gcnt[b];
    const int2* pp = pairs + (size_t)b * BCAP;
    for (int i = t; i < cnt; i += 256) atomicAdd(&hist[pp[i].y - d0], 1);
    __syncthreads();
    if (d0 + t < N) deg[d0 + t] = hist[t];
    if (d0 + t + 256 < N) deg[d0 + t + 256] = hist[t + 256];
}

__global__ void k_scan1(const int* __restrict__ deg, int* rowptr, int* bsum, int N) {
    __shared__ int lds[256];
    int t = threadIdx.x, n = blockIdx.x * 256 + t;
    int v = (n < N) ? deg[n] + 1 : 0;
    int xv = v;
    lds[t] = xv;
    __syncthreads();
    for (int off = 1; off < 256; off <<= 1) {
        int tmp = (t >= off) ? lds[t - off] : 0;
        __syncthreads();
        xv += tmp;
        lds[t] = xv;
        __syncthreads();
    }
    if (n < N) rowptr[n + 1] = xv;
    if (t == 255) bsum[blockIdx.x] = xv;
}

// scan3 computes its own exclusive prefix of bsum
__global__ void k_scan3(int* rowptr, const int* __restrict__ bsum, int N) {
    __shared__ int red[256];
    int t = threadIdx.x;
    int bid = blockIdx.x;
    int acc = 0;
    for (int k = t; k < bid; k += 256) acc += bsum[k];
    red[t] = acc;
    __syncthreads();
    for (int off = 128; off >= 1; off >>= 1) {
        if (t < off) red[t] += red[t + off];
        __syncthreads();
    }
    int pref = red[0];
    int n = bid * 256 + t;
    if (n < N) rowptr[n + 1] += pref;
    if (n == 0) rowptr[0] = 0;
}

__global__ __launch_bounds__(256) void k_bsort(const int2* __restrict__ pairs,
                                               const int* __restrict__ gcnt,
                                               const int* __restrict__ rowptr,
                                               int* __restrict__ eidx, int N) {
    __shared__ int curs[512];
    __shared__ int simg[SCAP];
    int t = threadIdx.x, b = blockIdx.x, d0 = b << BSHIFT;
    int d1 = min(d0 + 512, N);
    int seg0 = rowptr[d0], seg1 = rowptr[d1];
    int span = seg1 - seg0;
    int cnt = gcnt[b];
    const int2* pp = pairs + (size_t)b * BCAP;
    if (span <= SCAP) {
        for (int idx = t; idx < d1 - d0; idx += 256) {
            int rb = rowptr[d0 + idx], re = rowptr[d0 + idx + 1];
            curs[idx] = rb - seg0;
            simg[re - 1 - seg0] = d0 + idx;  // self loop at last slot
        }
        __syncthreads();
        for (int i = t; i < cnt; i += 256) {
            int2 q = pp[i];
            int r = atomicAdd(&curs[q.y - d0], 1);
            simg[r] = q.x;
        }
        __syncthreads();
        for (int i = t; i < span; i += 256) eidx[seg0 + i] = simg[i];
    } else {
        for (int idx = t; idx < d1 - d0; idx += 256) {
            curs[idx] = rowptr[d0 + idx];
            eidx[rowptr[d0 + idx + 1] - 1] = d0 + idx;
        }
        __syncthreads();
        for (int i = t; i < cnt; i += 256) {
            int2 q = pp[i];
            int r = atomicAdd(&curs[q.y - d0], 1);
            eidx[r] = q.x;
        }
    }
}

// ---------------- LDS fragment load ----------------
__device__ __forceinline__ bf16x8 lds_frag(const unsigned short* pp) {
    union { bf16x8 v; uint2 u2[2]; } t;
    t.u2[0] = *(const uint2*)pp;
    t.u2[1] = *(const uint2*)(pp + 4);
    return t.v;
}

// ---------------- tiled MFMA GEMM (optional fused attention scores / fused BN on A) ----
template <int K, bool BNA>
__global__ __launch_bounds__(256) void k_tgemm(const unsigned short* __restrict__ A,
                                               const float* __restrict__ Af,
                                               const float* __restrict__ bnA,
                                               const float* __restrict__ gammaA,
                                               const float* __restrict__ betaA,
                                               const unsigned short* __restrict__ WT,
                                               float* __restrict__ out,
                                               unsigned short* __restrict__ out16,
                                               const float* __restrict__ att_s,
                                               const float* __restrict__ att_d,
                                               float* __restrict__ a_s,
                                               float* __restrict__ a_d, int N) {
    __shared__ unsigned short Ast[64 * 36];
    __shared__ unsigned short Bst[128 * 36];
    __shared__ float bntab[BNA ? 512 : 1];
    const int tid = threadIdx.x;
    const int lane = tid & 63, w = tid >> 6;
    const int l16 = lane & 15, quad = lane >> 4;
    const int rowbase = blockIdx.x * 64;
    const int sar = tid >> 2, sak = tid & 3;
    const int sbc = tid >> 1, sbk = tid & 1;
    const long arow_g = min(rowbase + sar, N - 1);

    if constexpr (BNA) {
        if (tid < 128) {
            float invN = 1.f / (float)N;
            float mu = bnA[tid] * invN;
            float var = bnA[128 + tid] * invN - mu * mu;
            bntab[tid] = mu;
            bntab[128 + tid] = rsqrtf(var + EPS_BN);
            bntab[256 + tid] = gammaA[tid];
            bntab[384 + tid] = betaA[tid];
        }
        __syncthreads();
    }

    floatx4 acc[8];
#pragma unroll
    for (int c = 0; c < 8; c++) acc[c] = (floatx4){0.f, 0.f, 0.f, 0.f};

    const unsigned short* Ag = BNA ? nullptr : (A + (size_t)arow_g * K + sak * 8);
    const float* Agf = BNA ? (Af + (size_t)arow_g * 128 + sak * 8) : nullptr;
    const unsigned short* Bg = WT + (size_t)sbc * K + sbk * 8;

    auto loadA = [&](int k0) -> uint4 {
        if constexpr (BNA) {
            float4 v0 = *(const float4*)(Agf + k0);
            float4 v1 = *(const float4*)(Agf + k0 + 4);
            int c0 = sak * 8 + k0;
            unsigned short h[8];
#pragma unroll
            for (int j = 0; j < 4; j++) {
                int col = c0 + j;
                float y = ((((const float*)&v0)[j] - bntab[col]) * bntab[128 + col]) *
                              bntab[256 + col] + bntab[384 + col];
                y = y > 0.f ? y : __expf(y) - 1.f;
                h[j] = f2b(y);
            }
#pragma unroll
            for (int j = 0; j < 4; j++) {
                int col = c0 + 4 + j;
                float y = ((((const float*)&v1)[j] - bntab[col]) * bntab[128 + col]) *
                              bntab[256 + col] + bntab[384 + col];
                y = y > 0.f ? y : __expf(y) - 1.f;
                h[4 + j] = f2b(y);
            }
            uint4 r;
            r.x = (unsigned int)h[0] | ((unsigned int)h[1] << 16);
            r.y = (unsigned int)h[2] | ((unsigned int)h[3] << 16);
            r.z = (unsigned int)h[4] | ((unsigned int)h[5] << 16);
            r.w = (unsigned int)h[6] | ((unsigned int)h[7] << 16);
            return r;
        } else {
            return *(const uint4*)(Ag + k0);
        }
    };

    uint4 rA, rB0, rB1;
    rA = loadA(0);
    rB0 = *(const uint4*)(Bg);
    rB1 = *(const uint4*)(Bg + 16);

    unsigned short* Aw = Ast + sar * 36 + sak * 8;
    unsigned short* Bw0 = Bst + sbc * 36 + sbk * 8;
    unsigned short* Bw1 = Bw0 + 16;
    const unsigned short* Ar = Ast + (w * 16 + l16) * 36 + quad * 8;
    const unsigned short* Br = Bst + l16 * 36 + quad * 8;

#pragma unroll
    for (int k0 = 0; k0 < K; k0 += 32) {
        __syncthreads();
        *(uint2*)(Aw) = make_uint2(rA.x, rA.y);
        *(uint2*)(Aw + 4) = make_uint2(rA.z, rA.w);
        *(uint2*)(Bw0) = make_uint2(rB0.x, rB0.y);
        *(uint2*)(Bw0 + 4) = make_uint2(rB0.z, rB0.w);
        *(uint2*)(Bw1) = make_uint2(rB1.x, rB1.y);
        *(uint2*)(Bw1 + 4) = make_uint2(rB1.z, rB1.w);
        __syncthreads();
        if (k0 + 32 < K) {
            rA = loadA(k0 + 32);
            rB0 = *(const uint4*)(Bg + k0 + 32);
            rB1 = *(const uint4*)(Bg + k0 + 48);
        }
        bf16x8 af = lds_frag(Ar);
#pragma unroll
        for (int c = 0; c < 8; c++) {
            bf16x8 bf = lds_frag(Br + c * 16 * 36);
            acc[c] = __builtin_amdgcn_mfma_f32_16x16x32_bf16(af, bf, acc[c], 0, 0, 0);
        }
    }

    const int row00 = rowbase + w * 16 + quad * 4;
#pragma unroll
    for (int c = 0; c < 8; c++) {
#pragma unroll
        for (int r = 0; r < 4; r++) {
            int row = row00 + r;
            if (row < N) {
                if (out) out[(size_t)row * 128 + c * 16 + l16] = acc[c][r];
                if (out16) out16[(size_t)row * 128 + c * 16 + l16] = f2b(acc[c][r]);
            }
        }
    }
    if (att_s) {
        float asc[8], adc[8];
#pragma unroll
        for (int c = 0; c < 8; c++) {
            asc[c] = att_s[c * 16 + l16];
            adc[c] = att_d[c * 16 + l16];
        }
#pragma unroll
        for (int r = 0; r < 4; r++) {
            float ts[4] = {0.f, 0.f, 0.f, 0.f}, td[4] = {0.f, 0.f, 0.f, 0.f};
#pragma unroll
            for (int c = 0; c < 8; c++) {
                ts[c >> 1] += acc[c][r] * asc[c];
                td[c >> 1] += acc[c][r] * adc[c];
            }
#pragma unroll
            for (int off = 1; off < 16; off <<= 1) {
#pragma unroll
                for (int hh = 0; hh < 4; hh++) {
                    ts[hh] += __shfl_xor(ts[hh], off, 64);
                    td[hh] += __shfl_xor(td[hh], off, 64);
                }
            }
            int row = row00 + r;
            if (l16 == 0 && row < N) {
#pragma unroll
                for (int hh = 0; hh < 4; hh++) {
                    a_s[(size_t)row * 4 + hh] = ts[hh];
                    a_d[(size_t)row * 4 + hh] = td[hh];
                }
            }
        }
    }
}

// ---------------- single-dest fused softmax+accumulate, layers 0/1 (full wave) ----------------
__device__ __forceinline__ float2 facc01_one(int d, int lane, float4* pbw, int* sbw,
                                             const unsigned short* __restrict__ xp16,
                                             const float* __restrict__ a_s,
                                             const float* __restrict__ a_d,
                                             const int* __restrict__ rowptr,
                                             const int* __restrict__ eidx,
                                             const float* __restrict__ bias,
                                             float* __restrict__ out) {
    int hh = lane >> 4;
    float4 ad4 = *(const float4*)(a_d + (size_t)d * 4);
    int jb = rowptr[d], je = rowptr[d + 1], deg = je - jb;
    float a0 = 0.f, a1 = 0.f;
    float inv_h;
    if (deg <= 64) {
        int s = 0;
        float e0 = -INFINITY, e1 = -INFINITY, e2 = -INFINITY, e3 = -INFINITY;
        if (lane < deg) {
            s = eidx[jb + lane];
            float4 as4 = *(const float4*)(a_s + (size_t)s * 4);
            e0 = lrelu(as4.x + ad4.x);
            e1 = lrelu(as4.y + ad4.y);
            e2 = lrelu(as4.z + ad4.z);
            e3 = lrelu(as4.w + ad4.w);
        }
        float m0 = e0, m1 = e1, m2 = e2, m3 = e3;
        for (int off = 32; off >= 1; off >>= 1) {
            m0 = fmaxf(m0, __shfl_xor(m0, off, 64));
            m1 = fmaxf(m1, __shfl_xor(m1, off, 64));
            m2 = fmaxf(m2, __shfl_xor(m2, off, 64));
            m3 = fmaxf(m3, __shfl_xor(m3, off, 64));
        }
        float p0 = (lane < deg) ? __expf(e0 - m0) : 0.f;
        float p1 = (lane < deg) ? __expf(e1 - m1) : 0.f;
        float p2 = (lane < deg) ? __expf(e2 - m2) : 0.f;
        float p3 = (lane < deg) ? __expf(e3 - m3) : 0.f;
        float n0 = p0, n1 = p1, n2 = p2, n3 = p3;
        for (int off = 32; off >= 1; off >>= 1) {
            n0 += __shfl_xor(n0, off, 64);
            n1 += __shfl_xor(n1, off, 64);
            n2 += __shfl_xor(n2, off, 64);
            n3 += __shfl_xor(n3, off, 64);
        }
        inv_h = 1.f / (sel4(n0, n1, n2, n3, hh) + 1e-16f);
        if (lane < deg) {
            pbw[lane] = make_float4(p0, p1, p2, p3);
            sbw[lane] = s;
        }
        asm volatile("s_waitcnt lgkmcnt(0)" ::: "memory");
        __builtin_amdgcn_sched_barrier(0);
        int j = 0;
        for (; j + 4 <= deg; j += 4) {
            int s0 = __builtin_amdgcn_readfirstlane(sbw[j]);
            int s1 = __builtin_amdgcn_readfirstlane(sbw[j + 1]);
            int s2 = __builtin_amdgcn_readfirstlane(sbw[j + 2]);
            int s3 = __builtin_amdgcn_readfirstlane(sbw[j + 3]);
            float w0 = ((const float*)&pbw[j])[hh];
            float w1 = ((const float*)&pbw[j + 1])[hh];
            float w2 = ((const float*)&pbw[j + 2])[hh];
            float w3 = ((const float*)&pbw[j + 3])[hh];
            unsigned int u0 = *(const unsigned int*)(xp16 + (size_t)s0 * 128 + 2 * lane);
            unsigned int u1 = *(const unsigned int*)(xp16 + (size_t)s1 * 128 + 2 * lane);
            unsigned int u2 = *(const unsigned int*)(xp16 + (size_t)s2 * 128 + 2 * lane);
            unsigned int u3 = *(const unsigned int*)(xp16 + (size_t)s3 * 128 + 2 * lane);
            a0 += w0 * b2f_lo(u0) + w1 * b2f_lo(u1) + w2 * b2f_lo(u2) + w3 * b2f_lo(u3);
            a1 += w0 * b2f_hi(u0) + w1 * b2f_hi(u1) + w2 * b2f_hi(u2) + w3 * b2f_hi(u3);
        }
        for (; j < deg; ++j) {
            int sj = __builtin_amdgcn_readfirstlane(sbw[j]);
            float wj = ((const float*)&pbw[j])[hh];
            unsigned int u = *(const unsigned int*)(xp16 + (size_t)sj * 128 + 2 * lane);
            a0 += wj * b2f_lo(u);
            a1 += wj * b2f_hi(u);
        }
    } else {
        float m0 = -INFINITY, m1 = -INFINITY, m2 = -INFINITY, m3 = -INFINITY;
        for (int jj = jb + lane; jj < je; jj += 64) {
            int s = eidx[jj];
            float4 as4 = *(const float4*)(a_s + (size_t)s * 4);
            m0 = fmaxf(m0, lrelu(as4.x + ad4.x));
            m1 = fmaxf(m1, lrelu(as4.y + ad4.y));
            m2 = fmaxf(m2, lrelu(as4.z + ad4.z));
            m3 = fmaxf(m3, lrelu(as4.w + ad4.w));
        }
        for (int off = 32; off >= 1; off >>= 1) {
            m0 = fmaxf(m0, __shfl_xor(m0, off, 64));
            m1 = fmaxf(m1, __shfl_xor(m1, off, 64));
            m2 = fmaxf(m2, __shfl_xor(m2, off, 64));
            m3 = fmaxf(m3, __shfl_xor(m3, off, 64));
        }
        float n0 = 0.f, n1 = 0.f, n2 = 0.f, n3 = 0.f;
        for (int jj = jb + lane; jj < je; jj += 64) {
            int s = eidx[jj];
            float4 as4 = *(const float4*)(a_s + (size_t)s * 4);
            n0 += __expf(lrelu(as4.x + ad4.x) - m0);
            n1 += __expf(lrelu(as4.y + ad4.y) - m1);
            n2 += __expf(lrelu(as4.z + ad4.z) - m2);
            n3 += __expf(lrelu(as4.w + ad4.w) - m3);
        }
        for (int off = 32; off >= 1; off >>= 1) {
            n0 += __shfl_xor(n0, off, 64);
            n1 += __shfl_xor(n1, off, 64);
            n2 += __shfl_xor(n2, off, 64);
            n3 += __shfl_xor(n3, off, 64);
        }
        inv_h = 1.f / (sel4(n0, n1, n2, n3, hh) + 1e-16f);
        float m_h = sel4(m0, m1, m2, m3, hh);
        float ad_h = sel4(ad4.x, ad4.y, ad4.z, ad4.w, hh);
        for (int j = jb; j < je; ++j) {
            int s = __builtin_amdgcn_readfirstlane(eidx[j]);
            float4 as4 = *(const float4*)(a_s + (size_t)s * 4);
            float as_h = sel4(as4.x, as4.y, as4.z, as4.w, hh);
            float wj = __expf(lrelu(as_h + ad_h) - m_h);
            unsigned int u = *(const unsigned int*)(xp16 + (size_t)s * 128 + 2 * lane);
            a0 += wj * b2f_lo(u);
            a1 += wj * b2f_hi(u);
        }
    }
    float2 o = make_float2(a0 * inv_h + bias[2 * lane], a1 * inv_h + bias[2 * lane + 1]);
    *(float2*)(out + (size_t)d * 128 + 2 * lane) = o;
    return o;
}

// ---------------- FUSED softmax + accumulation + BN partials, layers 0/1 ----------------
__global__ __launch_bounds__(256) void k_facc01(const unsigned short* __restrict__ xp16,
                                                const float* __restrict__ a_s,
                                                const float* __restrict__ a_d,
                                                const int* __restrict__ rowptr,
                                                const int* __restrict__ eidx,
                                                const float* __restrict__ bias,
                                                float* __restrict__ out,
                                                float* __restrict__ partials, int N) {
    __shared__ float4 pb[4][64];
    __shared__ int sb[4][64];
    __shared__ float4 invb[4][2];
    __shared__ float bsl1[4][128], bsl2[4][128];
    int t = threadIdx.x;
    int w = t >> 6, lane = t & 63;
    int base = (blockIdx.x * 4 + w) * 2;
    float s1lo = 0.f, s1hi = 0.f, s2lo = 0.f, s2hi = 0.f;
    if (base < N) {
        bool have2 = (base + 1 < N);
        int half = lane >> 5, l32 = lane & 31;
        int hh = lane >> 4;
        int dh = base + (have2 ? half : 0);
        int jbh = rowptr[dh], jeh = rowptr[dh + 1];
        int degh = jeh - jbh;
        if (have2 && __all(degh <= 32)) {
            // ---- pass 1: half-wave per dest ----
            float4 ad4 = *(const float4*)(a_d + (size_t)dh * 4);
            int s = 0;
            float e0 = -INFINITY, e1 = -INFINITY, e2 = -INFINITY, e3 = -INFINITY;
            if (l32 < degh) {
                s = eidx[jbh + l32];
                float4 as4 = *(const float4*)(a_s + (size_t)s * 4);
                e0 = lrelu(as4.x + ad4.x);
                e1 = lrelu(as4.y + ad4.y);
                e2 = lrelu(as4.z + ad4.z);
                e3 = lrelu(as4.w + ad4.w);
            }
            // prefetch first 4-edge block per dest (loads overlap softmax)
            int sa0 = __builtin_amdgcn_readfirstlane(__shfl(s, 0, 64));
            int sa1 = __builtin_amdgcn_readfirstlane(__shfl(s, 1, 64));
            int sa2 = __builtin_amdgcn_readfirstlane(__shfl(s, 2, 64));
            int sa3 = __builtin_amdgcn_readfirstlane(__shfl(s, 3, 64));
            int sb0 = __builtin_amdgcn_readfirstlane(__shfl(s, 32, 64));
            int sb1 = __builtin_amdgcn_readfirstlane(__shfl(s, 33, 64));
            int sb2 = __builtin_amdgcn_readfirstlane(__shfl(s, 34, 64));
            int sb3 = __builtin_amdgcn_readfirstlane(__shfl(s, 35, 64));
            unsigned int upA0 = *(const unsigned int*)(xp16 + (size_t)sa0 * 128 + 2 * lane);
            unsigned int upA1 = *(const unsigned int*)(xp16 + (size_t)sa1 * 128 + 2 * lane);
            unsigned int upA2 = *(const unsigned int*)(xp16 + (size_t)sa2 * 128 + 2 * lane);
            unsigned int upA3 = *(const unsigned int*)(xp16 + (size_t)sa3 * 128 + 2 * lane);
            unsigned int upB0 = *(const unsigned int*)(xp16 + (size_t)sb0 * 128 + 2 * lane);
            unsigned int upB1 = *(const unsigned int*)(xp16 + (size_t)sb1 * 128 + 2 * lane);
            unsigned int upB2 = *(const unsigned int*)(xp16 + (size_t)sb2 * 128 + 2 * lane);
            unsigned int upB3 = *(const unsigned int*)(xp16 + (size_t)sb3 * 128 + 2 * lane);
            float m0 = e0, m1 = e1, m2 = e2, m3 = e3;
            for (int off = 16; off >= 1; off >>= 1) {
                m0 = fmaxf(m0, __shfl_xor(m0, off, 32));
                m1 = fmaxf(m1, __shfl_xor(m1, off, 32));
                m2 = fmaxf(m2, __shfl_xor(m2, off, 32));
                m3 = fmaxf(m3, __shfl_xor(m3, off, 32));
            }
            float p0 = (l32 < degh) ? __expf(e0 - m0) : 0.f;
            float p1 = (l32 < degh) ? __expf(e1 - m1) : 0.f;
            float p2 = (l32 < degh) ? __expf(e2 - m2) : 0.f;
            float p3 = (l32 < degh) ? __expf(e3 - m3) : 0.f;
            float n0 = p0, n1 = p1, n2 = p2, n3 = p3;
            for (int off = 16; off >= 1; off >>= 1) {
                n0 += __shfl_xor(n0, off, 32);
                n1 += __shfl_xor(n1, off, 32);
                n2 += __shfl_xor(n2, off, 32);
                n3 += __shfl_xor(n3, off, 32);
            }
            if (l32 == 0)
                invb[w][half] = make_float4(1.f / (n0 + 1e-16f), 1.f / (n1 + 1e-16f),
                                            1.f / (n2 + 1e-16f), 1.f / (n3 + 1e-16f));
            if (l32 < degh) {
                pb[w][half * 32 + l32] = make_float4(p0, p1, p2, p3);
                sb[w][half * 32 + l32] = s;
            }
            asm volatile("s_waitcnt lgkmcnt(0)" ::: "memory");
            __builtin_amdgcn_sched_barrier(0);
            int deg0 = __shfl(degh, 0, 64);
            int deg1 = __shfl(degh, 32, 64);
            // ---- pass 2: full wave, one dest at a time ----
#pragma unroll
            for (int tt = 0; tt < 2; ++tt) {
                int degt = tt ? deg1 : deg0;
                const float4* pbt = &pb[w][tt * 32];
                const int* sbt = &sb[w][tt * 32];
                float a0 = 0.f, a1 = 0.f;
                int j = 0;
                if (degt >= 4) {  // first block consumes the prefetched loads
                    float w0 = ((const float*)&pbt[0])[hh];
                    float w1 = ((const float*)&pbt[1])[hh];
                    float w2 = ((const float*)&pbt[2])[hh];
                    float w3 = ((const float*)&pbt[3])[hh];
                    unsigned int u0 = tt ? upB0 : upA0;
                    unsigned int u1 = tt ? upB1 : upA1;
                    unsigned int u2 = tt ? upB2 : upA2;
                    unsigned int u3 = tt ? upB3 : upA3;
                    a0 += w0 * b2f_lo(u0) + w1 * b2f_lo(u1) + w2 * b2f_lo(u2) + w3 * b2f_lo(u3);
                    a1 += w0 * b2f_hi(u0) + w1 * b2f_hi(u1) + w2 * b2f_hi(u2) + w3 * b2f_hi(u3);
                    j = 4;
                }
                for (; j + 4 <= degt; j += 4) {
                    int s0 = __builtin_amdgcn_readfirstlane(sbt[j]);
                    int s1 = __builtin_amdgcn_readfirstlane(sbt[j + 1]);
                    int s2 = __builtin_amdgcn_readfirstlane(sbt[j + 2]);
                    int s3 = __builtin_amdgcn_readfirstlane(sbt[j + 3]);
                    float w0 = ((const float*)&pbt[j])[hh];
                    float w1 = ((const float*)&pbt[j + 1])[hh];
                    float w2 = ((const float*)&pbt[j + 2])[hh];
                    float w3 = ((const float*)&pbt[j + 3])[hh];
                    unsigned int u0 = *(const unsigned int*)(xp16 + (size_t)s0 * 128 + 2 * lane);
                    unsigned int u1 = *(const unsigned int*)(xp16 + (size_t)s1 * 128 + 2 * lane);
                    unsigned int u2 = *(const unsigned int*)(xp16 + (size_t)s2 * 128 + 2 * lane);
                    unsigned int u3 = *(const unsigned int*)(xp16 + (size_t)s3 * 128 + 2 * lane);
                    a0 += w0 * b2f_lo(u0) + w1 * b2f_lo(u1) + w2 * b2f_lo(u2) + w3 * b2f_lo(u3);
                    a1 += w0 * b2f_hi(u0) + w1 * b2f_hi(u1) + w2 * b2f_hi(u2) + w3 * b2f_hi(u3);
                }
                for (; j < degt; ++j) {
                    int sj = __builtin_amdgcn_readfirstlane(sbt[j]);
                    float wj = ((const float*)&pbt[j])[hh];
                    unsigned int u = *(const unsigned int*)(xp16 + (size_t)sj * 128 + 2 * lane);
                    a0 += wj * b2f_lo(u);
                    a1 += wj * b2f_hi(u);
                }
                float inv = ((const float*)&invb[w][tt])[hh];
                float2 o = make_float2(a0 * inv + bias[2 * lane], a1 * inv + bias[2 * lane + 1]);
                *(float2*)(out + (size_t)(base + tt) * 128 + 2 * lane) = o;
                s1lo += o.x; s1hi += o.y;
                s2lo += o.x * o.x; s2hi += o.y * o.y;
            }
        } else {
            float2 oA = facc01_one(base, lane, pb[w], sb[w], xp16, a_s, a_d, rowptr, eidx,
                                   bias, out);
            s1lo += oA.x; s1hi += oA.y;
            s2lo += oA.x * oA.x; s2hi += oA.y * oA.y;
            if (have2) {
                float2 oB = facc01_one(base + 1, lane, pb[w], sb[w], xp16, a_s, a_d, rowptr,
                                       eidx, bias, out);
                s1lo += oB.x; s1hi += oB.y;
                s2lo += oB.x * oB.x; s2hi += oB.y * oB.y;
            }
        }
    }
    // ---- atomic-free BN partials: per-wave slots -> cross-wave reduce -> global row ----
    bsl1[w][2 * lane] = s1lo;
    bsl1[w][2 * lane + 1] = s1hi;
    bsl2[w][2 * lane] = s2lo;
    bsl2[w][2 * lane + 1] = s2hi;
    __syncthreads();
    if (t < 128) {
        float p1 = bsl1[0][t] + bsl1[1][t] + bsl1[2][t] + bsl1[3][t];
        float p2 = bsl2[0][t] + bsl2[1][t] + bsl2[2][t] + bsl2[3][t];
        partials[(size_t)blockIdx.x * 256 + t] = p1;
        partials[(size_t)blockIdx.x * 256 + 128 + t] = p2;
    }
}

// ---------------- BN partial reduce (high-occupancy, 4-deep pipelined) ----------------
__global__ void k_bnred(const float* __restrict__ partials, float* __restrict__ sums,
                        int nblk) {
    int c = threadIdx.x;  // 256, coalesced across a row
    int G = gridDim.x;
    float a0 = 0.f, a1 = 0.f, a2 = 0.f, a3 = 0.f;
    int b = blockIdx.x;
    for (; b + 3 * G < nblk; b += 4 * G) {
        a0 += partials[(size_t)b * 256 + c];
        a1 += partials[(size_t)(b + G) * 256 + c];
        a2 += partials[(size_t)(b + 2 * G) * 256 + c];
        a3 += partials[(size_t)(b + 3 * G) * 256 + c];
    }
    for (; b < nblk; b += G) a0 += partials[(size_t)b * 256 + c];
    atomicAdd(&sums[c], (a0 + a1) + (a2 + a3));
}

// ---------------- single-dest fused softmax+accumulate, layer 2 (full wave) ----------------
__device__ __forceinline__ void faccL2_one(int d, int lane, float4* pbw, int* sbw,
                                           const unsigned short* __restrict__ hb16,
                                           const float* __restrict__ a_s,
                                           const float* __restrict__ a_d,
                                           const int* __restrict__ rowptr,
                                           const int* __restrict__ eidx,
                                           unsigned short* __restrict__ agg16) {
    float4 ad4 = *(const float4*)(a_d + (size_t)d * 4);
    int jb = rowptr[d], je = rowptr[d + 1], deg = je - jb;
    float acc[4][2] = {{0.f, 0.f}, {0.f, 0.f}, {0.f, 0.f}, {0.f, 0.f}};
    float iv0, iv1, iv2, iv3;
    if (deg <= 64) {
        int s = 0;
        float e0 = -INFINITY, e1 = -INFINITY, e2 = -INFINITY, e3 = -INFINITY;
        if (lane < deg) {
            s = eidx[jb + lane];
            float4 as4 = *(const float4*)(a_s + (size_t)s * 4);
            e0 = lrelu(as4.x + ad4.x);
            e1 = lrelu(as4.y + ad4.y);
            e2 = lrelu(as4.z + ad4.z);
            e3 = lrelu(as4.w + ad4.w);
        }
        float m0 = e0, m1 = e1, m2 = e2, m3 = e3;
        for (int off = 32; off >= 1; off >>= 1) {
            m0 = fmaxf(m0, __shfl_xor(m0, off, 64));
            m1 = fmaxf(m1, __shfl_xor(m1, off, 64));
            m2 = fmaxf(m2, __shfl_xor(m2, off, 64));
            m3 = fmaxf(m3, __shfl_xor(m3, off, 64));
        }
        float p0 = (lane < deg) ? __expf(e0 - m0) : 0.f;
        float p1 = (lane < deg) ? __expf(e1 - m1) : 0.f;
        float p2 = (lane < deg) ? __expf(e2 - m2) : 0.f;
        float p3 = (lane < deg) ? __expf(e3 - m3) : 0.f;
        float n0 = p0, n1 = p1, n2 = p2, n3 = p3;
        for (int off = 32; off >= 1; off >>= 1) {
            n0 += __shfl_xor(n0, off, 64);
            n1 += __shfl_xor(n1, off, 64);
            n2 += __shfl_xor(n2, off, 64);
            n3 += __shfl_xor(n3, off, 64);
        }
        iv0 = 1.f / (n0 + 1e-16f);
        iv1 = 1.f / (n1 + 1e-16f);
        iv2 = 1.f / (n2 + 1e-16f);
        iv3 = 1.f / (n3 + 1e-16f);
        if (lane < deg) {
            pbw[lane] = make_float4(p0, p1, p2, p3);
            sbw[lane] = s;
        }
        asm volatile("s_waitcnt lgkmcnt(0)" ::: "memory");
        __builtin_amdgcn_sched_barrier(0);
        int j = 0;
        for (; j + 4 <= deg; j += 4) {
            int s0 = __builtin_amdgcn_readfirstlane(sbw[j]);
            int s1 = __builtin_amdgcn_readfirstlane(sbw[j + 1]);
            int s2 = __builtin_amdgcn_readfirstlane(sbw[j + 2]);
            int s3 = __builtin_amdgcn_readfirstlane(sbw[j + 3]);
            float4 w0 = pbw[j], w1 = pbw[j + 1], w2 = pbw[j + 2], w3 = pbw[j + 3];
            unsigned int u0 = *(const unsigned int*)(hb16 + (size_t)s0 * 128 + 2 * lane);
            unsigned int u1 = *(const unsigned int*)(hb16 + (size_t)s1 * 128 + 2 * lane);
            unsigned int u2 = *(const unsigned int*)(hb16 + (size_t)s2 * 128 + 2 * lane);
            unsigned int u3 = *(const unsigned int*)(hb16 + (size_t)s3 * 128 + 2 * lane);
            float lo0 = b2f_lo(u0), hi0 = b2f_hi(u0);
            float lo1 = b2f_lo(u1), hi1 = b2f_hi(u1);
            float lo2 = b2f_lo(u2), hi2 = b2f_hi(u2);
            float lo3 = b2f_lo(u3), hi3 = b2f_hi(u3);
#pragma unroll
            for (int hh = 0; hh < 4; hh++) {
                acc[hh][0] += ((const float*)&w0)[hh] * lo0 + ((const float*)&w1)[hh] * lo1 +
                              ((const float*)&w2)[hh] * lo2 + ((const float*)&w3)[hh] * lo3;
                acc[hh][1] += ((const float*)&w0)[hh] * hi0 + ((const float*)&w1)[hh] * hi1 +
                              ((const float*)&w2)[hh] * hi2 + ((const float*)&w3)[hh] * hi3;
            }
        }
        for (; j < deg; ++j) {
            int sj = __builtin_amdgcn_readfirstlane(sbw[j]);
            float4 wj = pbw[j];
            unsigned int u = *(const unsigned int*)(hb16 + (size_t)sj * 128 + 2 * lane);
            float lo = b2f_lo(u), hi = b2f_hi(u);
#pragma unroll
            for (int hh = 0; hh < 4; hh++) {
                acc[hh][0] += ((const float*)&wj)[hh] * lo;
                acc[hh][1] += ((const float*)&wj)[hh] * hi;
            }
        }
    } else {
        float m0 = -INFINITY, m1 = -INFINITY, m2 = -INFINITY, m3 = -INFINITY;
        for (int jj = jb + lane; jj < je; jj += 64) {
            int s = eidx[jj];
            float4 as4 = *(const float4*)(a_s + (size_t)s * 4);
            m0 = fmaxf(m0, lrelu(as4.x + ad4.x));
            m1 = fmaxf(m1, lrelu(as4.y + ad4.y));
            m2 = fmaxf(m2, lrelu(as4.z + ad4.z));
            m3 = fmaxf(m3, lrelu(as4.w + ad4.w));
        }
        for (int off = 32; off >= 1; off >>= 1) {
            m0 = fmaxf(m0, __shfl_xor(m0, off, 64));
            m1 = fmaxf(m1, __shfl_xor(m1, off, 64));
            m2 = fmaxf(m2, __shfl_xor(m2, off, 64));
            m3 = fmaxf(m3, __shfl_xor(m3, off, 64));
        }
        float n0 = 0.f, n1 = 0.f, n2 = 0.f, n3 = 0.f;
        for (int jj = jb + lane; jj < je; jj += 64) {
            int s = eidx[jj];
            float4 as4 = *(const float4*)(a_s + (size_t)s * 4);
            n0 += __expf(lrelu(as4.x + ad4.x) - m0);
            n1 += __expf(lrelu(as4.y + ad4.y) - m1);
            n2 += __expf(lrelu(as4.z + ad4.z) - m2);
            n3 += __expf(lrelu(as4.w + ad4.w) - m3);
        }
        for (int off = 32; off >= 1; off >>= 1) {
            n0 += __shfl_xor(n0, off, 64);
            n1 += __shfl_xor(n1, off, 64);
            n2 += __shfl_xor(n2, off, 64);
            n3 += __shfl_xor(n3, off, 64);
        }
        iv0 = 1.f / (n0 + 1e-16f);
        iv1 = 1.f / (n1 + 1e-16f);
        iv2 = 1.f / (n2 + 1e-16f);
        iv3 = 1.f / (n3 + 1e-16f);
        for (int j = jb; j < je; ++j) {
            int s = __builtin_amdgcn_readfirstlane(eidx[j]);
            float4 as4 = *(const float4*)(a_s + (size_t)s * 4);
            float w0 = __expf(lrelu(as4.x + ad4.x) - m0);
            float w1 = __expf(lrelu(as4.y + ad4.y) - m1);
            float w2 = __expf(lrelu(as4.z + ad4.z) - m2);
            float w3 = __expf(lrelu(as4.w + ad4.w) - m3);
            unsigned int u = *(const unsigned int*)(hb16 + (size_t)s * 128 + 2 * lane);
            float lo = b2f_lo(u), hi = b2f_hi(u);
            acc[0][0] += w0 * lo; acc[0][1] += w0 * hi;
            acc[1][0] += w1 * lo; acc[1][1] += w1 * hi;
            acc[2][0] += w2 * lo; acc[2][1] += w2 * hi;
            acc[3][0] += w3 * lo; acc[3][1] += w3 * hi;
        }
    }
    float iv[4] = {iv0, iv1, iv2, iv3};
#pragma unroll
    for (int hh = 0; hh < 4; hh++) {
        ushort2 o = make_ushort2(f2b(acc[hh][0] * iv[hh]), f2b(acc[hh][1] * iv[hh]));
        *(ushort2*)(agg16 + (size_t)d * 512 + hh * 128 + 2 * lane) = o;
    }
}

// ---------------- FUSED softmax + accumulation, layer 2 (2 dests per wave) ----------------
__global__ __launch_bounds__(256) void k_faccL2(const unsigned short* __restrict__ hb16,
                                                const float* __restrict__ a_s,
                                                const float* __restrict__ a_d,
                                                const int* __restrict__ rowptr,
                                                const int* __restrict__ eidx,
                                                unsigned short* __restrict__ agg16, int N) {
    __shared__ float4 pb[4][64];
    __shared__ int sb[4][64];
    __shared__ float4 invb[4][2];
    int w = threadIdx.x >> 6, lane = threadIdx.x & 63;
    int base = (blockIdx.x * 4 + w) * 2;
    if (base >= N) return;
    bool have2 = (base + 1 < N);
    int half = lane >> 5, l32 = lane & 31;
    int dh = base + (have2 ? half : 0);
    int jbh = rowptr[dh], jeh = rowptr[dh + 1];
    int degh = jeh - jbh;
    if (have2 && __all(degh <= 32)) {
        // ---- pass 1: half-wave per dest ----
        float4 ad4 = *(const float4*)(a_d + (size_t)dh * 4);
        int s = 0;
        float e0 = -INFINITY, e1 = -INFINITY, e2 = -INFINITY, e3 = -INFINITY;
        if (l32 < degh) {
            s = eidx[jbh + l32];
            float4 as4 = *(const float4*)(a_s + (size_t)s * 4);
            e0 = lrelu(as4.x + ad4.x);
            e1 = lrelu(as4.y + ad4.y);
            e2 = lrelu(as4.z + ad4.z);
            e3 = lrelu(as4.w + ad4.w);
        }
        // prefetch first 4-edge block per dest
        int sa0 = __builtin_amdgcn_readfirstlane(__shfl(s, 0, 64));
        int sa1 = __builtin_amdgcn_readfirstlane(__shfl(s, 1, 64));
        int sa2 = __builtin_amdgcn_readfirstlane(__shfl(s, 2, 64));
        int sa3 = __builtin_amdgcn_readfirstlane(__shfl(s, 3, 64));
        int sb0 = __builtin_amdgcn_readfirstlane(__shfl(s, 32, 64));
        int sb1 = __builtin_amdgcn_readfirstlane(__shfl(s, 33, 64));
        int sb2 = __builtin_amdgcn_readfirstlane(__shfl(s, 34, 64));
        int sb3 = __builtin_amdgcn_readfirstlane(__shfl(s, 35, 64));
        unsigned int upA0 = *(const unsigned int*)(hb16 + (size_t)sa0 * 128 + 2 * lane);
        unsigned int upA1 = *(const unsigned int*)(hb16 + (size_t)sa1 * 128 + 2 * lane);
        unsigned int upA2 = *(const unsigned int*)(hb16 + (size_t)sa2 * 128 + 2 * lane);
        unsigned int upA3 = *(const unsigned int*)(hb16 + (size_t)sa3 * 128 + 2 * lane);
        unsigned int upB0 = *(const unsigned int*)(hb16 + (size_t)sb0 * 128 + 2 * lane);
        unsigned int upB1 = *(const unsigned int*)(hb16 + (size_t)sb1 * 128 + 2 * lane);
        unsigned int upB2 = *(const unsigned int*)(hb16 + (size_t)sb2 * 128 + 2 * lane);
        unsigned int upB3 = *(const unsigned int*)(hb16 + (size_t)sb3 * 128 + 2 * lane);
        float m0 = e0, m1 = e1, m2 = e2, m3 = e3;
        for (int off = 16; off >= 1; off >>= 1) {
            m0 = fmaxf(m0, __shfl_xor(m0, off, 32));
            m1 = fmaxf(m1, __shfl_xor(m1, off, 32));
            m2 = fmaxf(m2, __shfl_xor(m2, off, 32));
            m3 = fmaxf(m3, __shfl_xor(m3, off, 32));
        }
        float p0 = (l32 < degh) ? __expf(e0 - m0) : 0.f;
        float p1 = (l32 < degh) ? __expf(e1 - m1) : 0.f;
        float p2 = (l32 < degh) ? __expf(e2 - m2) : 0.f;
        float p3 = (l32 < degh) ? __expf(e3 - m3) : 0.f;
        float n0 = p0, n1 = p1, n2 = p2, n3 = p3;
        for (int off = 16; off >= 1; off >>= 1) {
            n0 += __shfl_xor(n0, off, 32);
            n1 += __shfl_xor(n1, off, 32);
            n2 += __shfl_xor(n2, off, 32);
            n3 += __shfl_xor(n3, off, 32);
        }
        if (l32 == 0)
            invb[w][half] = make_float4(1.f / (n0 + 1e-16f), 1.f / (n1 + 1e-16f),
                                        1.f / (n2 + 1e-16f), 1.f / (n3 + 1e-16f));
        if (l32 < degh) {
            pb[w][half * 32 + l32] = make_float4(p0, p1, p2, p3);
            sb[w][half * 32 + l32] = s;
        }
        asm volatile("s_waitcnt lgkmcnt(0)" ::: "memory");
        __builtin_amdgcn_sched_barrier(0);
        int deg0 = __shfl(degh, 0, 64);
        int deg1 = __shfl(degh, 32, 64);
        // ---- pass 2: full wave, one dest at a time ----
#pragma unroll
        for (int t = 0; t < 2; ++t) {
            int degt = t ? deg1 : deg0;
            const float4* pbt = &pb[w][t * 32];
            const int* sbt = &sb[w][t * 32];
            float acc[4][2] = {{0.f, 0.f}, {0.f, 0.f}, {0.f, 0.f}, {0.f, 0.f}};
            int j = 0;
            if (degt >= 4) {  // first block consumes the prefetched loads
                float4 w0 = pbt[0], w1 = pbt[1], w2 = pbt[2], w3 = pbt[3];
                unsigned int u0 = t ? upB0 : upA0;
                unsigned int u1 = t ? upB1 : upA1;
                unsigned int u2 = t ? upB2 : upA2;
                unsigned int u3 = t ? upB3 : upA3;
                float lo0 = b2f_lo(u0), hi0 = b2f_hi(u0);
                float lo1 = b2f_lo(u1), hi1 = b2f_hi(u1);
                float lo2 = b2f_lo(u2), hi2 = b2f_hi(u2);
                float lo3 = b2f_lo(u3), hi3 = b2f_hi(u3);
#pragma unroll
                for (int hh = 0; hh < 4; hh++) {
                    acc[hh][0] += ((const float*)&w0)[hh] * lo0 + ((const float*)&w1)[hh] * lo1 +
                                  ((const float*)&w2)[hh] * lo2 + ((const float*)&w3)[hh] * lo3;
                    acc[hh][1] += ((const float*)&w0)[hh] * hi0 + ((const float*)&w1)[hh] * hi1 +
                                  ((const float*)&w2)[hh] * hi2 + ((const float*)&w3)[hh] * hi3;
                }
                j = 4;
            }
            for (; j + 4 <= degt; j += 4) {
                int s0 = __builtin_amdgcn_readfirstlane(sbt[j]);
                int s1 = __builtin_amdgcn_readfirstlane(sbt[j + 1]);
                int s2 = __builtin_amdgcn_readfirstlane(sbt[j + 2]);
                int s3 = __builtin_amdgcn_readfirstlane(sbt[j + 3]);
                float4 w0 = pbt[j], w1 = pbt[j + 1], w2 = pbt[j + 2], w3 = pbt[j + 3];
                unsigned int u0 = *(const unsigned int*)(hb16 + (size_t)s0 * 128 + 2 * lane);
                unsigned int u1 = *(const unsigned int*)(hb16 + (size_t)s1 * 128 + 2 * lane);
                unsigned int u2 = *(const unsigned int*)(hb16 + (size_t)s2 * 128 + 2 * lane);
                unsigned int u3 = *(const unsigned int*)(hb16 + (size_t)s3 * 128 + 2 * lane);
                float lo0 = b2f_lo(u0), hi0 = b2f_hi(u0);
                float lo1 = b2f_lo(u1), hi1 = b2f_hi(u1);
                float lo2 = b2f_lo(u2), hi2 = b2f_hi(u2);
                float lo3 = b2f_lo(u3), hi3 = b2f_hi(u3);
#pragma unroll
                for (int hh = 0; hh < 4; hh++) {
                    acc[hh][0] += ((const float*)&w0)[hh] * lo0 + ((const float*)&w1)[hh] * lo1 +
                                  ((const float*)&w2)[hh] * lo2 + ((const float*)&w3)[hh] * lo3;
                    acc[hh][1] += ((const float*)&w0)[hh] * hi0 + ((const float*)&w1)[hh] * hi1 +
                                  ((const float*)&w2)[hh] * hi2 + ((const float*)&w3)[hh] * hi3;
                }
            }
            for (; j < degt; ++j) {
                int sj = __builtin_amdgcn_readfirstlane(sbt[j]);
                float4 wj = pbt[j];
                unsigned int u = *(const unsigned int*)(hb16 + (size_t)sj * 128 + 2 * lane);
                float lo = b2f_lo(u), hi = b2f_hi(u);
#pragma unroll
                for (int hh = 0; hh < 4; hh++) {
                    acc[hh][0] += ((const float*)&wj)[hh] * lo;
                    acc[hh][1] += ((const float*)&wj)[hh] * hi;
                }
            }
            float4 ivv = invb[w][t];
            const float* iv = (const float*)&ivv;
#pragma unroll
            for (int hh = 0; hh < 4; hh++) {
                ushort2 o = make_ushort2(f2b(acc[hh][0] * iv[hh]), f2b(acc[hh][1] * iv[hh]));
                *(ushort2*)(agg16 + (size_t)(base + t) * 512 + hh * 128 + 2 * lane) = o;
            }
        }
    } else {
        faccL2_one(base, lane, pb[w], sb[w], hb16, a_s, a_d, rowptr, eidx, agg16);
        if (have2)
            faccL2_one(base + 1, lane, pb[w], sb[w], hb16, a_s, a_d, rowptr, eidx, agg16);
    }
}

// ---------------- batch norm (layer 2 only) ----------------
__global__ void k_bnstats(const float* __restrict__ x, float* __restrict__ sums, int N) {
    int col = threadIdx.x & 127, half = threadIdx.x >> 7;
    float s1 = 0.f, s2 = 0.f;
    for (int r = blockIdx.x * 2 + half; r < N; r += gridDim.x * 2) {
        float v = x[(size_t)r * 128 + col];
        s1 += v;
        s2 += v * v;
    }
    atomicAdd(&sums[col], s1);
    atomicAdd(&sums[128 + col], s2);
}

__global__ void k_bnapply(float* __restrict__ x, unsigned short* __restrict__ out16,
                          const float* __restrict__ sums, const float* __restrict__ gamma,
                          const float* __restrict__ beta, int N, int elu, int writex) {
    int idx = blockIdx.x * blockDim.x + threadIdx.x;
    if (idx >= N * 32) return;
    float4 v = ((float4*)x)[idx];
    int colb = (idx & 31) * 4;
    float invN = 1.f / (float)N;
#pragma unroll
    for (int j = 0; j < 4; j++) {
        int col = colb + j;
        float mu = sums[col] * invN;
        float var = sums[128 + col] * invN - mu * mu;
        float y = (((float*)&v)[j] - mu) * rsqrtf(var + EPS_BN) * gamma[col] + beta[col];
        if (elu) y = y > 0.f ? y : __expf(y) - 1.f;
        ((float*)&v)[j] = y;
    }
    if (writex) ((float4*)x)[idx] = v;
    if (out16) {
        ushort4 o = make_ushort4(f2b(v.x), f2b(v.y), f2b(v.z), f2b(v.w));
        ((ushort4*)out16)[idx] = o;
    }
}

// ---------------- fused BN+ELU+bf16 + layer-2 attention scores (layer 1 only) ----------------
__global__ __launch_bounds__(256) void k_bnapply_att(const float* __restrict__ x,
                                                     unsigned short* __restrict__ out16,
                                                     const float* __restrict__ sums,
                                                     const float* __restrict__ gamma,
                                                     const float* __restrict__ beta,
                                                     const float* __restrict__ Wt,
                                                     float* __restrict__ a_s,
                                                     float* __restrict__ a_d, int N) {
    int wid = (blockIdx.x * blockDim.x + threadIdx.x) >> 6;
    int lane = threadIdx.x & 63;
    if (wid >= N) return;
    float invN = 1.f / (float)N;
    int c0 = lane, c1 = 64 + lane;
    float v0 = x[(size_t)wid * 128 + c0];
    float v1 = x[(size_t)wid * 128 + c1];
    float mu0 = sums[c0] * invN;
    float var0 = sums[128 + c0] * invN - mu0 * mu0;
    float y0 = (v0 - mu0) * rsqrtf(var0 + EPS_BN) * gamma[c0] + beta[c0];
    float mu1 = sums[c1] * invN;
    float var1 = sums[128 + c1] * invN - mu1 * mu1;
    float y1 = (v1 - mu1) * rsqrtf(var1 + EPS_BN) * gamma[c1] + beta[c1];
    y0 = y0 > 0.f ? y0 : __expf(y0) - 1.f;
    y1 = y1 > 0.f ? y1 : __expf(y1) - 1.f;
    out16[(size_t)wid * 128 + c0] = f2b(y0);
    out16[(size_t)wid * 128 + c1] = f2b(y1);
    float ts[4], td[4];
#pragma unroll
    for (int hh = 0; hh < 4; hh++) {
        ts[hh] = y0 * Wt[hh * 128 + lane] + y1 * Wt[hh * 128 + 64 + lane];
        td[hh] = y0 * Wt[512 + hh * 128 + lane] + y1 * Wt[512 + hh * 128 + 64 + lane];
    }
    for (int m = 32; m >= 1; m >>= 1) {
#pragma unroll
        for (int hh = 0; hh < 4; hh++) {
            ts[hh] += __shfl_xor(ts[hh], m, 64);
            td[hh] += __shfl_xor(td[hh], m, 64);
        }
    }
    if (lane == 0) {
#pragma unroll
        for (int hh = 0; hh < 4; hh++) {
            a_s[wid * 4 + hh] = ts[hh];
            a_d[wid * 4 + hh] = td[hh];
        }
    }
}

// ---------------- launch ----------------
extern "C" void kernel_launch(void* const* d_in, const int* in_sizes, int n_in,
                              void* d_out, int out_size, void* d_ws, size_t ws_size,
                              hipStream_t stream) {
    const float* x = (const float*)d_in[0];
    const int* ei_raw = (const int*)d_in[1];
    const float* W0 = (const float*)d_in[2];
    const float* as0 = (const float*)d_in[3];
    const float* ad0 = (const float*)d_in[4];
    const float* b0 = (const float*)d_in[5];
    const float* g0 = (const float*)d_in[6];
    const float* be0 = (const float*)d_in[7];
    const float* W1 = (const float*)d_in[8];
    const float* as1 = (const float*)d_in[9];
    const float* ad1 = (const float*)d_in[10];
    const float* b1 = (const float*)d_in[11];
    const float* g1 = (const float*)d_in[12];
    const float* be1 = (const float*)d_in[13];
    const float* W2 = (const float*)d_in[14];
    const float* as2 = (const float*)d_in[15];
    const float* ad2 = (const float*)d_in[16];
    const float* g2v = (const float*)d_in[18];
    const float* be2 = (const float*)d_in[19];

    const int N = in_sizes[0] / 128;
    const int E = in_sizes[1] / 2;
    const int gw2 = (N + 7) / 8;

    // workspace carve (256B aligned)
    char* p = (char*)d_ws;
    auto alloc = [&](size_t bytes) {
        void* r = (void*)p;
        p += (bytes + 255) & ~(size_t)255;
        return r;
    };
    float* hbuf = (float*)alloc((size_t)N * 128 * 4);
    unsigned short* xb = (unsigned short*)alloc((size_t)N * 128 * 2);
    unsigned short* xp16 = (unsigned short*)alloc((size_t)N * 128 * 2);
    unsigned short* hb16 = (unsigned short*)alloc((size_t)N * 128 * 2);
    unsigned short* agg16 = (unsigned short*)alloc((size_t)N * 512 * 2);
    float* As = (float*)alloc((size_t)N * 4 * 4);
    float* Ad = (float*)alloc((size_t)N * 4 * 4);
    int* deg = (int*)alloc((size_t)N * 4);
    int* rowptr = (int*)alloc((size_t)(N + 1) * 4);
    int* bsum = (int*)alloc(1024);
    int* eidx = (int*)alloc((size_t)(E + N) * 4);
    float* bns = (float*)alloc(768 * 4);  // 3 slots of 256
    int* flag = (int*)alloc(256);
    float* Wt = (float*)alloc(1024 * 4);
    unsigned short* WT0 = (unsigned short*)alloc((size_t)128 * 128 * 2);
    unsigned short* WT1 = (unsigned short*)alloc((size_t)128 * 128 * 2);
    unsigned short* WT2 = (unsigned short*)alloc((size_t)128 * 512 * 2);
    float* partials = (float*)alloc((size_t)gw2 * 256 * 4);
    int2* pairs = (int2*)alloc((size_t)NBUK * BCAP * 8);
    int* gcnt = (int*)alloc(NBUK * 4);
    if ((size_t)(p - (char*)d_ws) > ws_size) return;

    const int nb = (N + 255) / 256;
    const int gw = (N + 3) / 4;
    const int gt = (N + 63) / 64;
    const int nbuk_used = (N + (1 << BSHIFT) - 1) >> BSHIFT;
    const int binB = (E + 1023) / 1024;
    const int prepB = 640 + (N * 32 + 255) / 256;

    // --- CSR build (bucketed, LDS-sorted); detect zeroes gcnt + bns; prep fused into bin ---
    k_detect64<<<1, 64, 0, stream>>>(ei_raw, flag, 2 * E, gcnt, bns);
    k_bin_prep<<<binB + prepB, 256, 0, stream>>>(ei_raw, flag, E, gcnt, pairs, binB, W0, W1,
                                                 W2, as2, ad2, WT0, WT1, WT2, Wt, x, xb,
                                                 N * 32);
    k_bdeg2<<<nbuk_used, 256, 0, stream>>>(pairs, gcnt, deg, N);
    k_scan1<<<nb, 256, 0, stream>>>(deg, rowptr, bsum, N);
    k_scan3<<<nb, 256, 0, stream>>>(rowptr, bsum, N);
    k_bsort<<<nbuk_used, 256, 0, stream>>>(pairs, gcnt, rowptr, eidx, N);

    // --- layer 0 (GEMM fuses attention scores; softmax + BN partials fused into accumulate) ---
    k_tgemm<128, false><<<gt, 256, 0, stream>>>(xb, (const float*)nullptr,
                                                (const float*)nullptr, (const float*)nullptr,
                                                (const float*)nullptr, WT0, (float*)nullptr,
                                                xp16, as0, ad0, As, Ad, N);
    k_facc01<<<gw2, 256, 0, stream>>>(xp16, As, Ad, rowptr, eidx, b0, hbuf, partials, N);
    k_bnred<<<256, 256, 0, stream>>>(partials, bns, gw2);
    // L0 BN+ELU+cast fused into L1 GEMM A-load (hb16 round-trip removed)

    // --- layer 1 (A = BN(hbuf) inline; BN+ELU fused with layer-2 attention scores) ---
    k_tgemm<128, true><<<gt, 256, 0, stream>>>((const unsigned short*)nullptr, hbuf, bns, g0,
                                               be0, WT1, (float*)nullptr, xp16, as1, ad1, As,
                                               Ad, N);
    k_facc01<<<gw2, 256, 0, stream>>>(xp16, As, Ad, rowptr, eidx, b1, hbuf, partials, N);
    k_bnred<<<256, 256, 0, stream>>>(partials, bns + 256, gw2);
    k_bnapply_att<<<gw, 256, 0, stream>>>(hbuf, hb16, bns + 256, g1, be1, Wt, As, Ad, N);

    // --- layer 2 ---
    float* outf = (float*)d_out;
    k_faccL2<<<gw2, 256, 0, stream>>>(hb16, As, Ad, rowptr, eidx, agg16, N);
    k_tgemm<512, false><<<gt, 256, 0, stream>>>(agg16, (const float*)nullptr,
                                                (const float*)nullptr, (const float*)nullptr,
                                                (const float*)nullptr, WT2, outf,
                                                (unsigned short*)nullptr, (const float*)nullptr,
                                                (const float*)nullptr, (float*)nullptr,
                                                (float*)nullptr, N);
    k_bnstats<<<256, 256, 0, stream>>>(outf, bns + 512, N);
    k_bnapply<<<(N * 32 + 255) / 256, 256, 0, stream>>>(outf, (unsigned short*)nullptr,
                                                        bns + 512, g2v, be2, N, 0, 1);
}

// Round 14
// 403.518 us; speedup vs baseline: 1.2967x; 1.0671x over previous
//
#include <hip/hip_runtime.h>
#include <math.h>

#define EPS_BN 1e-5f
#define NBUK 128
#define BSHIFT 9
#define BCAP 16384
#define SCAP 14336

typedef __bf16 bf16x8 __attribute__((ext_vector_type(8)));
typedef float floatx4 __attribute__((ext_vector_type(4)));

__device__ __forceinline__ float lrelu(float x) { return x > 0.f ? x : 0.2f * x; }

__device__ __forceinline__ unsigned short f2b(float f) {
    unsigned int b = __float_as_uint(f);
    b = (b + 0x7fffu + ((b >> 16) & 1u)) >> 16;
    return (unsigned short)b;
}
__device__ __forceinline__ float b2f_lo(unsigned int u) { return __uint_as_float(u << 16); }
__device__ __forceinline__ float b2f_hi(unsigned int u) { return __uint_as_float(u & 0xffff0000u); }

__device__ __forceinline__ float sel4(float a, float b, float c, float d, int h) {
    return h < 2 ? (h == 0 ? a : b) : (h == 2 ? c : d);
}

// ---------------- edge dtype probe + workspace zeroing ----------------
__global__ void k_detect64(const int* __restrict__ ei, int* flag, int nwords,
                           int* __restrict__ gcnt, float* __restrict__ bns) {
    int lane = threadIdx.x;  // 64
    int lim = nwords < 512 ? nwords : 512;
    int zeros = 0;
    for (int i = 2 * lane + 1; i < lim; i += 128) zeros += (ei[i] == 0);
    for (int off = 32; off >= 1; off >>= 1) zeros += __shfl_xor(zeros, off, 64);
    if (lane == 0) *flag = (zeros > lim / 8) ? 1 : 0;
    for (int i = lane; i < NBUK; i += 64) gcnt[i] = 0;
    for (int i = lane; i < 768; i += 64) bns[i] = 0.f;
}

// ---------------- bucketed CSR build: bin edges + (fused) weight prep ----------------
__global__ __launch_bounds__(256) void k_bin_prep(
    const int* __restrict__ ei, const int* __restrict__ flag, int E,
    int* __restrict__ gcnt, int2* __restrict__ pairs, int binB,
    const float* __restrict__ W0, const float* __restrict__ W1,
    const float* __restrict__ W2, const float* __restrict__ as2,
    const float* __restrict__ ad2, unsigned short* __restrict__ WT0,
    unsigned short* __restrict__ WT1, unsigned short* __restrict__ WT2,
    float* __restrict__ Wt, const float* __restrict__ x,
    unsigned short* __restrict__ xb, int n4) {
    if (blockIdx.x >= binB) {
        int bid = blockIdx.x - binB;
        if (bid < 64) {
            int idx = bid * 256 + threadIdx.x;  // 16384 total
            int c = idx >> 7, k = idx & 127;
            WT0[idx] = f2b(W0[(size_t)k * 128 + c]);
        } else if (bid < 128) {
            int idx = (bid - 64) * 256 + threadIdx.x;
            int c = idx >> 7, k = idx & 127;
            WT1[idx] = f2b(W1[(size_t)k * 128 + c]);
        } else if (bid < 384) {
            int idx = (bid - 128) * 256 + threadIdx.x;  // 65536 total
            int c = idx >> 9, j = idx & 511;
            WT2[idx] = f2b(0.25f * W2[(size_t)(j & 127) * 512 + (j >> 7) * 128 + c]);
        } else if (bid < 640) {
            int wid = ((bid - 384) * 256 + threadIdx.x) >> 6;
            int lane = threadIdx.x & 63;
            if (wid < 1024) {
                int k = wid & 127, hh = (wid >> 7) & 3, isd = wid >> 9;
                const float* att = isd ? ad2 : as2;
                float v = W2[(size_t)k * 512 + hh * 128 + lane] * att[hh * 128 + lane] +
                          W2[(size_t)k * 512 + hh * 128 + 64 + lane] * att[hh * 128 + 64 + lane];
                for (int m = 32; m >= 1; m >>= 1) v += __shfl_xor(v, m, 64);
                if (lane == 0) Wt[isd * 512 + hh * 128 + k] = v;
            }
        } else {
            int i = (bid - 640) * 256 + threadIdx.x;
            if (i < n4) {
                float4 v = ((const float4*)x)[i];
                ushort4 o = make_ushort4(f2b(v.x), f2b(v.y), f2b(v.z), f2b(v.w));
                ((ushort4*)xb)[i] = o;
            }
        }
        return;
    }
    __shared__ int hist[NBUK], cnt2[NBUK], startb[NBUK], gbase[NBUK], sc[NBUK];
    __shared__ int2 stage[1024];
    int t = threadIdx.x;
    int e0 = blockIdx.x * 1024;
    int nblk = min(1024, E - e0);
    int f = *flag;
    if (t < NBUK) { hist[t] = 0; cnt2[t] = 0; }
    __syncthreads();
    int2 pr[4];
    int bb[4], m = 0;
    int idx0 = e0 + t * 4;
    if (idx0 + 4 <= E) {
        int4 s, d;
        if (f) {
            s = make_int4(ei[2 * idx0], ei[2 * idx0 + 2], ei[2 * idx0 + 4], ei[2 * idx0 + 6]);
            d = make_int4(ei[2 * (E + idx0)], ei[2 * (E + idx0) + 2],
                          ei[2 * (E + idx0) + 4], ei[2 * (E + idx0) + 6]);
        } else {
            s = *(const int4*)(ei + idx0);
            d = *(const int4*)(ei + E + idx0);
        }
        pr[0] = make_int2(s.x, d.x); pr[1] = make_int2(s.y, d.y);
        pr[2] = make_int2(s.z, d.z); pr[3] = make_int2(s.w, d.w);
        m = 4;
    } else {
        for (int i = idx0; i < E; ++i)
            pr[m++] = make_int2(f ? ei[2 * i] : ei[i], f ? ei[2 * (E + i)] : ei[E + i]);
    }
#pragma unroll
    for (int k = 0; k < 4; k++)
        if (k < m) { bb[k] = pr[k].y >> BSHIFT; atomicAdd(&hist[bb[k]], 1); }
    __syncthreads();
    if (t < NBUK) sc[t] = hist[t];
    __syncthreads();
    for (int off = 1; off < NBUK; off <<= 1) {
        int v = 0;
        if (t < NBUK && t >= off) v = sc[t - off];
        __syncthreads();
        if (t < NBUK) sc[t] += v;
        __syncthreads();
    }
    if (t < NBUK) {
        startb[t] = sc[t] - hist[t];
        gbase[t] = hist[t] ? atomicAdd(&gcnt[t], hist[t]) : 0;
    }
    __syncthreads();
#pragma unroll
    for (int k = 0; k < 4; k++)
        if (k < m) {
            int r = atomicAdd(&cnt2[bb[k]], 1);
            stage[startb[bb[k]] + r] = pr[k];
        }
    __syncthreads();
    for (int i = t; i < nblk; i += 256) {
        int2 q = stage[i];
        int b = q.y >> BSHIFT;
        pairs[(size_t)b * BCAP + gbase[b] + (i - startb[b])] = q;
    }
}

__global__ __launch_bounds__(256) void k_bdeg2(const int2* __restrict__ pairs,
                                               const int* __restrict__ gcnt,
                                               int* __restrict__ deg, int N) {
    __shared__ int hist[512];
    int t = threadIdx.x, b = blockIdx.x, d0 = b << BSHIFT;
    hist[t] = 0; hist[t + 256] = 0;
    __syncthreads();
    int cnt = gcnt[b];
    const int2* pp = pairs + (size_t)b * BCAP;
    for (int i = t; i < cnt; i += 256) atomicAdd(&hist[pp[i].y - d0], 1);
    __syncthreads();
    if (d0 + t < N) deg[d0 + t] = hist[t];
    if (d0 + t + 256 < N) deg[d0 + t + 256] = hist[t + 256];
}

__global__ void k_scan1(const int* __restrict__ deg, int* rowptr, int* bsum, int N) {
    __shared__ int lds[256];
    int t = threadIdx.x, n = blockIdx.x * 256 + t;
    int v = (n < N) ? deg[n] + 1 : 0;
    int xv = v;
    lds[t] = xv;
    __syncthreads();
    for (int off = 1; off < 256; off <<= 1) {
        int tmp = (t >= off) ? lds[t - off] : 0;
        __syncthreads();
        xv += tmp;
        lds[t] = xv;
        __syncthreads();
    }
    if (n < N) rowptr[n + 1] = xv;
    if (t == 255) bsum[blockIdx.x] = xv;
}

// scan3 computes its own exclusive prefix of bsum
__global__ void k_scan3(int* rowptr, const int* __restrict__ bsum, int N) {
    __shared__ int red[256];
    int t = threadIdx.x;
    int bid = blockIdx.x;
    int acc = 0;
    for (int k = t; k < bid; k += 256) acc += bsum[k];
    red[t] = acc;
    __syncthreads();
    for (int off = 128; off >= 1; off >>= 1) {
        if (t < off) red[t] += red[t + off];
        __syncthreads();
    }
    int pref = red[0];
    int n = bid * 256 + t;
    if (n < N) rowptr[n + 1] += pref;
    if (n == 0) rowptr[0] = 0;
}

__global__ __launch_bounds__(256) void k_bsort(const int2* __restrict__ pairs,
                                               const int* __restrict__ gcnt,
                                               const int* __restrict__ rowptr,
                                               int* __restrict__ eidx, int N) {
    __shared__ int curs[512];
    __shared__ int simg[SCAP];
    int t = threadIdx.x, b = blockIdx.x, d0 = b << BSHIFT;
    int d1 = min(d0 + 512, N);
    int seg0 = rowptr[d0], seg1 = rowptr[d1];
    int span = seg1 - seg0;
    int cnt = gcnt[b];
    const int2* pp = pairs + (size_t)b * BCAP;
    if (span <= SCAP) {
        for (int idx = t; idx < d1 - d0; idx += 256) {
            int rb = rowptr[d0 + idx], re = rowptr[d0 + idx + 1];
            curs[idx] = rb - seg0;
            simg[re - 1 - seg0] = d0 + idx;  // self loop at last slot
        }
        __syncthreads();
        for (int i = t; i < cnt; i += 256) {
            int2 q = pp[i];
            int r = atomicAdd(&curs[q.y - d0], 1);
            simg[r] = q.x;
        }
        __syncthreads();
        for (int i = t; i < span; i += 256) eidx[seg0 + i] = simg[i];
    } else {
        for (int idx = t; idx < d1 - d0; idx += 256) {
            curs[idx] = rowptr[d0 + idx];
            eidx[rowptr[d0 + idx + 1] - 1] = d0 + idx;
        }
        __syncthreads();
        for (int i = t; i < cnt; i += 256) {
            int2 q = pp[i];
            int r = atomicAdd(&curs[q.y - d0], 1);
            eidx[r] = q.x;
        }
    }
}

// ---------------- LDS fragment load ----------------
__device__ __forceinline__ bf16x8 lds_frag(const unsigned short* pp) {
    union { bf16x8 v; uint2 u2[2]; } t;
    t.u2[0] = *(const uint2*)pp;
    t.u2[1] = *(const uint2*)(pp + 4);
    return t.v;
}

// ---------------- tiled MFMA GEMM (fused attn scores / BN-on-A / BN partials out) ----
template <int K, bool BNA>
__global__ __launch_bounds__(256) void k_tgemm(const unsigned short* __restrict__ A,
                                               const float* __restrict__ Af,
                                               const float* __restrict__ bnA,
                                               const float* __restrict__ gammaA,
                                               const float* __restrict__ betaA,
                                               const unsigned short* __restrict__ WT,
                                               float* __restrict__ out,
                                               unsigned short* __restrict__ out16,
                                               const float* __restrict__ att_s,
                                               const float* __restrict__ att_d,
                                               float* __restrict__ a_s,
                                               float* __restrict__ a_d, int N,
                                               float* __restrict__ bnpart) {
    __shared__ unsigned short Ast[64 * 36];
    __shared__ unsigned short Bst[128 * 36];
    __shared__ float bntab[BNA ? 512 : 1];
    const int tid = threadIdx.x;
    const int lane = tid & 63, w = tid >> 6;
    const int l16 = lane & 15, quad = lane >> 4;
    const int rowbase = blockIdx.x * 64;
    const int sar = tid >> 2, sak = tid & 3;
    const int sbc = tid >> 1, sbk = tid & 1;
    const long arow_g = min(rowbase + sar, N - 1);

    if constexpr (BNA) {
        if (tid < 128) {
            float invN = 1.f / (float)N;
            float mu = bnA[tid] * invN;
            float var = bnA[128 + tid] * invN - mu * mu;
            bntab[tid] = mu;
            bntab[128 + tid] = rsqrtf(var + EPS_BN);
            bntab[256 + tid] = gammaA[tid];
            bntab[384 + tid] = betaA[tid];
        }
        __syncthreads();
    }

    floatx4 acc[8];
#pragma unroll
    for (int c = 0; c < 8; c++) acc[c] = (floatx4){0.f, 0.f, 0.f, 0.f};

    const unsigned short* Ag = BNA ? nullptr : (A + (size_t)arow_g * K + sak * 8);
    const float* Agf = BNA ? (Af + (size_t)arow_g * 128 + sak * 8) : nullptr;
    const unsigned short* Bg = WT + (size_t)sbc * K + sbk * 8;

    auto loadA = [&](int k0) -> uint4 {
        if constexpr (BNA) {
            float4 v0 = *(const float4*)(Agf + k0);
            float4 v1 = *(const float4*)(Agf + k0 + 4);
            int c0 = sak * 8 + k0;
            unsigned short h[8];
#pragma unroll
            for (int j = 0; j < 4; j++) {
                int col = c0 + j;
                float y = ((((const float*)&v0)[j] - bntab[col]) * bntab[128 + col]) *
                              bntab[256 + col] + bntab[384 + col];
                y = y > 0.f ? y : __expf(y) - 1.f;
                h[j] = f2b(y);
            }
#pragma unroll
            for (int j = 0; j < 4; j++) {
                int col = c0 + 4 + j;
                float y = ((((const float*)&v1)[j] - bntab[col]) * bntab[128 + col]) *
                              bntab[256 + col] + bntab[384 + col];
                y = y > 0.f ? y : __expf(y) - 1.f;
                h[4 + j] = f2b(y);
            }
            uint4 r;
            r.x = (unsigned int)h[0] | ((unsigned int)h[1] << 16);
            r.y = (unsigned int)h[2] | ((unsigned int)h[3] << 16);
            r.z = (unsigned int)h[4] | ((unsigned int)h[5] << 16);
            r.w = (unsigned int)h[6] | ((unsigned int)h[7] << 16);
            return r;
        } else {
            return *(const uint4*)(Ag + k0);
        }
    };

    uint4 rA, rB0, rB1;
    rA = loadA(0);
    rB0 = *(const uint4*)(Bg);
    rB1 = *(const uint4*)(Bg + 16);

    unsigned short* Aw = Ast + sar * 36 + sak * 8;
    unsigned short* Bw0 = Bst + sbc * 36 + sbk * 8;
    unsigned short* Bw1 = Bw0 + 16;
    const unsigned short* Ar = Ast + (w * 16 + l16) * 36 + quad * 8;
    const unsigned short* Br = Bst + l16 * 36 + quad * 8;

#pragma unroll
    for (int k0 = 0; k0 < K; k0 += 32) {
        __syncthreads();
        *(uint2*)(Aw) = make_uint2(rA.x, rA.y);
        *(uint2*)(Aw + 4) = make_uint2(rA.z, rA.w);
        *(uint2*)(Bw0) = make_uint2(rB0.x, rB0.y);
        *(uint2*)(Bw0 + 4) = make_uint2(rB0.z, rB0.w);
        *(uint2*)(Bw1) = make_uint2(rB1.x, rB1.y);
        *(uint2*)(Bw1 + 4) = make_uint2(rB1.z, rB1.w);
        __syncthreads();
        if (k0 + 32 < K) {
            rA = loadA(k0 + 32);
            rB0 = *(const uint4*)(Bg + k0 + 32);
            rB1 = *(const uint4*)(Bg + k0 + 48);
        }
        bf16x8 af = lds_frag(Ar);
#pragma unroll
        for (int c = 0; c < 8; c++) {
            bf16x8 bf = lds_frag(Br + c * 16 * 36);
            acc[c] = __builtin_amdgcn_mfma_f32_16x16x32_bf16(af, bf, acc[c], 0, 0, 0);
        }
    }

    const int row00 = rowbase + w * 16 + quad * 4;
#pragma unroll
    for (int c = 0; c < 8; c++) {
#pragma unroll
        for (int r = 0; r < 4; r++) {
            int row = row00 + r;
            if (row < N) {
                if (out) out[(size_t)row * 128 + c * 16 + l16] = acc[c][r];
                if (out16) out16[(size_t)row * 128 + c * 16 + l16] = f2b(acc[c][r]);
            }
        }
    }
    if (att_s) {
        float asc[8], adc[8];
#pragma unroll
        for (int c = 0; c < 8; c++) {
            asc[c] = att_s[c * 16 + l16];
            adc[c] = att_d[c * 16 + l16];
        }
#pragma unroll
        for (int r = 0; r < 4; r++) {
            float ts[4] = {0.f, 0.f, 0.f, 0.f}, td[4] = {0.f, 0.f, 0.f, 0.f};
#pragma unroll
            for (int c = 0; c < 8; c++) {
                ts[c >> 1] += acc[c][r] * asc[c];
                td[c >> 1] += acc[c][r] * adc[c];
            }
#pragma unroll
            for (int off = 1; off < 16; off <<= 1) {
#pragma unroll
                for (int hh = 0; hh < 4; hh++) {
                    ts[hh] += __shfl_xor(ts[hh], off, 64);
                    td[hh] += __shfl_xor(td[hh], off, 64);
                }
            }
            int row = row00 + r;
            if (l16 == 0 && row < N) {
#pragma unroll
                for (int hh = 0; hh < 4; hh++) {
                    a_s[(size_t)row * 4 + hh] = ts[hh];
                    a_d[(size_t)row * 4 + hh] = td[hh];
                }
            }
        }
    }
    if (bnpart) {
        // atomic-free BN partials: per-thread col sums -> quad shuffle-reduce ->
        // per-wave LDS slots (reuse dead Ast after a uniform barrier) -> one
        // coalesced 256-float partial row per block.
        float ts1[8], ts2[8];
#pragma unroll
        for (int c = 0; c < 8; c++) { ts1[c] = 0.f; ts2[c] = 0.f; }
#pragma unroll
        for (int c = 0; c < 8; c++) {
#pragma unroll
            for (int r = 0; r < 4; r++) {
                int row = row00 + r;
                if (row < N) {
                    float v = acc[c][r];
                    ts1[c] += v;
                    ts2[c] += v * v;
                }
            }
        }
#pragma unroll
        for (int c = 0; c < 8; c++) {
            ts1[c] += __shfl_xor(ts1[c], 16, 64);
            ts1[c] += __shfl_xor(ts1[c], 32, 64);
            ts2[c] += __shfl_xor(ts2[c], 16, 64);
            ts2[c] += __shfl_xor(ts2[c], 32, 64);
        }
        float* wred = (float*)Ast;  // 1024 floats needed, Ast has 1152
        __syncthreads();            // all waves done reading Ast (uniform, no early returns)
        if (quad == 0) {
#pragma unroll
            for (int c = 0; c < 8; c++) {
                wred[w * 256 + c * 16 + l16] = ts1[c];
                wred[w * 256 + 128 + c * 16 + l16] = ts2[c];
            }
        }
        __syncthreads();
        float p = wred[tid] + wred[256 + tid] + wred[512 + tid] + wred[768 + tid];
        bnpart[(size_t)blockIdx.x * 256 + tid] = p;
    }
}

// ---------------- single-dest fused softmax+accumulate, layers 0/1 (full wave) ----------------
__device__ __forceinline__ float2 facc01_one(int d, int lane, float4* pbw, int* sbw,
                                             const unsigned short* __restrict__ xp16,
                                             const float* __restrict__ a_s,
                                             const float* __restrict__ a_d,
                                             const int* __restrict__ rowptr,
                                             const int* __restrict__ eidx,
                                             const float* __restrict__ bias,
                                             float* __restrict__ out) {
    int hh = lane >> 4;
    float4 ad4 = *(const float4*)(a_d + (size_t)d * 4);
    int jb = rowptr[d], je = rowptr[d + 1], deg = je - jb;
    float a0 = 0.f, a1 = 0.f;
    float inv_h;
    if (deg <= 64) {
        int s = 0;
        float e0 = -INFINITY, e1 = -INFINITY, e2 = -INFINITY, e3 = -INFINITY;
        if (lane < deg) {
            s = eidx[jb + lane];
            float4 as4 = *(const float4*)(a_s + (size_t)s * 4);
            e0 = lrelu(as4.x + ad4.x);
            e1 = lrelu(as4.y + ad4.y);
            e2 = lrelu(as4.z + ad4.z);
            e3 = lrelu(as4.w + ad4.w);
        }
        float m0 = e0, m1 = e1, m2 = e2, m3 = e3;
        for (int off = 32; off >= 1; off >>= 1) {
            m0 = fmaxf(m0, __shfl_xor(m0, off, 64));
            m1 = fmaxf(m1, __shfl_xor(m1, off, 64));
            m2 = fmaxf(m2, __shfl_xor(m2, off, 64));
            m3 = fmaxf(m3, __shfl_xor(m3, off, 64));
        }
        float p0 = (lane < deg) ? __expf(e0 - m0) : 0.f;
        float p1 = (lane < deg) ? __expf(e1 - m1) : 0.f;
        float p2 = (lane < deg) ? __expf(e2 - m2) : 0.f;
        float p3 = (lane < deg) ? __expf(e3 - m3) : 0.f;
        float n0 = p0, n1 = p1, n2 = p2, n3 = p3;
        for (int off = 32; off >= 1; off >>= 1) {
            n0 += __shfl_xor(n0, off, 64);
            n1 += __shfl_xor(n1, off, 64);
            n2 += __shfl_xor(n2, off, 64);
            n3 += __shfl_xor(n3, off, 64);
        }
        inv_h = 1.f / (sel4(n0, n1, n2, n3, hh) + 1e-16f);
        if (lane < deg) {
            pbw[lane] = make_float4(p0, p1, p2, p3);
            sbw[lane] = s;
        }
        asm volatile("s_waitcnt lgkmcnt(0)" ::: "memory");
        __builtin_amdgcn_sched_barrier(0);
        int j = 0;
        for (; j + 4 <= deg; j += 4) {
            int s0 = __builtin_amdgcn_readfirstlane(sbw[j]);
            int s1 = __builtin_amdgcn_readfirstlane(sbw[j + 1]);
            int s2 = __builtin_amdgcn_readfirstlane(sbw[j + 2]);
            int s3 = __builtin_amdgcn_readfirstlane(sbw[j + 3]);
            float w0 = ((const float*)&pbw[j])[hh];
            float w1 = ((const float*)&pbw[j + 1])[hh];
            float w2 = ((const float*)&pbw[j + 2])[hh];
            float w3 = ((const float*)&pbw[j + 3])[hh];
            unsigned int u0 = *(const unsigned int*)(xp16 + (size_t)s0 * 128 + 2 * lane);
            unsigned int u1 = *(const unsigned int*)(xp16 + (size_t)s1 * 128 + 2 * lane);
            unsigned int u2 = *(const unsigned int*)(xp16 + (size_t)s2 * 128 + 2 * lane);
            unsigned int u3 = *(const unsigned int*)(xp16 + (size_t)s3 * 128 + 2 * lane);
            a0 += w0 * b2f_lo(u0) + w1 * b2f_lo(u1) + w2 * b2f_lo(u2) + w3 * b2f_lo(u3);
            a1 += w0 * b2f_hi(u0) + w1 * b2f_hi(u1) + w2 * b2f_hi(u2) + w3 * b2f_hi(u3);
        }
        for (; j < deg; ++j) {
            int sj = __builtin_amdgcn_readfirstlane(sbw[j]);
            float wj = ((const float*)&pbw[j])[hh];
            unsigned int u = *(const unsigned int*)(xp16 + (size_t)sj * 128 + 2 * lane);
            a0 += wj * b2f_lo(u);
            a1 += wj * b2f_hi(u);
        }
    } else {
        float m0 = -INFINITY, m1 = -INFINITY, m2 = -INFINITY, m3 = -INFINITY;
        for (int jj = jb + lane; jj < je; jj += 64) {
            int s = eidx[jj];
            float4 as4 = *(const float4*)(a_s + (size_t)s * 4);
            m0 = fmaxf(m0, lrelu(as4.x + ad4.x));
            m1 = fmaxf(m1, lrelu(as4.y + ad4.y));
            m2 = fmaxf(m2, lrelu(as4.z + ad4.z));
            m3 = fmaxf(m3, lrelu(as4.w + ad4.w));
        }
        for (int off = 32; off >= 1; off >>= 1) {
            m0 = fmaxf(m0, __shfl_xor(m0, off, 64));
            m1 = fmaxf(m1, __shfl_xor(m1, off, 64));
            m2 = fmaxf(m2, __shfl_xor(m2, off, 64));
            m3 = fmaxf(m3, __shfl_xor(m3, off, 64));
        }
        float n0 = 0.f, n1 = 0.f, n2 = 0.f, n3 = 0.f;
        for (int jj = jb + lane; jj < je; jj += 64) {
            int s = eidx[jj];
            float4 as4 = *(const float4*)(a_s + (size_t)s * 4);
            n0 += __expf(lrelu(as4.x + ad4.x) - m0);
            n1 += __expf(lrelu(as4.y + ad4.y) - m1);
            n2 += __expf(lrelu(as4.z + ad4.z) - m2);
            n3 += __expf(lrelu(as4.w + ad4.w) - m3);
        }
        for (int off = 32; off >= 1; off >>= 1) {
            n0 += __shfl_xor(n0, off, 64);
            n1 += __shfl_xor(n1, off, 64);
            n2 += __shfl_xor(n2, off, 64);
            n3 += __shfl_xor(n3, off, 64);
        }
        inv_h = 1.f / (sel4(n0, n1, n2, n3, hh) + 1e-16f);
        float m_h = sel4(m0, m1, m2, m3, hh);
        float ad_h = sel4(ad4.x, ad4.y, ad4.z, ad4.w, hh);
        for (int j = jb; j < je; ++j) {
            int s = __builtin_amdgcn_readfirstlane(eidx[j]);
            float4 as4 = *(const float4*)(a_s + (size_t)s * 4);
            float as_h = sel4(as4.x, as4.y, as4.z, as4.w, hh);
            float wj = __expf(lrelu(as_h + ad_h) - m_h);
            unsigned int u = *(const unsigned int*)(xp16 + (size_t)s * 128 + 2 * lane);
            a0 += wj * b2f_lo(u);
            a1 += wj * b2f_hi(u);
        }
    }
    float2 o = make_float2(a0 * inv_h + bias[2 * lane], a1 * inv_h + bias[2 * lane + 1]);
    *(float2*)(out + (size_t)d * 128 + 2 * lane) = o;
    return o;
}

// ---------------- FUSED softmax + accumulation + BN partials, layers 0/1 ----------------
__global__ __launch_bounds__(256) void k_facc01(const unsigned short* __restrict__ xp16,
                                                const float* __restrict__ a_s,
                                                const float* __restrict__ a_d,
                                                const int* __restrict__ rowptr,
                                                const int* __restrict__ eidx,
                                                const float* __restrict__ bias,
                                                float* __restrict__ out,
                                                float* __restrict__ partials, int N) {
    __shared__ float4 pb[4][64];
    __shared__ int sb[4][64];
    __shared__ float4 invb[4][2];
    __shared__ float bsl1[4][128], bsl2[4][128];
    int t = threadIdx.x;
    int w = t >> 6, lane = t & 63;
    int base = (blockIdx.x * 4 + w) * 2;
    float s1lo = 0.f, s1hi = 0.f, s2lo = 0.f, s2hi = 0.f;
    if (base < N) {
        bool have2 = (base + 1 < N);
        int half = lane >> 5, l32 = lane & 31;
        int hh = lane >> 4;
        int dh = base + (have2 ? half : 0);
        int jbh = rowptr[dh], jeh = rowptr[dh + 1];
        int degh = jeh - jbh;
        if (have2 && __all(degh <= 32)) {
            // ---- pass 1: half-wave per dest ----
            float4 ad4 = *(const float4*)(a_d + (size_t)dh * 4);
            int s = 0;
            float e0 = -INFINITY, e1 = -INFINITY, e2 = -INFINITY, e3 = -INFINITY;
            if (l32 < degh) {
                s = eidx[jbh + l32];
                float4 as4 = *(const float4*)(a_s + (size_t)s * 4);
                e0 = lrelu(as4.x + ad4.x);
                e1 = lrelu(as4.y + ad4.y);
                e2 = lrelu(as4.z + ad4.z);
                e3 = lrelu(as4.w + ad4.w);
            }
            // prefetch first 4-edge block per dest (loads overlap softmax)
            int sa0 = __builtin_amdgcn_readfirstlane(__shfl(s, 0, 64));
            int sa1 = __builtin_amdgcn_readfirstlane(__shfl(s, 1, 64));
            int sa2 = __builtin_amdgcn_readfirstlane(__shfl(s, 2, 64));
            int sa3 = __builtin_amdgcn_readfirstlane(__shfl(s, 3, 64));
            int sb0 = __builtin_amdgcn_readfirstlane(__shfl(s, 32, 64));
            int sb1 = __builtin_amdgcn_readfirstlane(__shfl(s, 33, 64));
            int sb2 = __builtin_amdgcn_readfirstlane(__shfl(s, 34, 64));
            int sb3 = __builtin_amdgcn_readfirstlane(__shfl(s, 35, 64));
            unsigned int upA0 = *(const unsigned int*)(xp16 + (size_t)sa0 * 128 + 2 * lane);
            unsigned int upA1 = *(const unsigned int*)(xp16 + (size_t)sa1 * 128 + 2 * lane);
            unsigned int upA2 = *(const unsigned int*)(xp16 + (size_t)sa2 * 128 + 2 * lane);
            unsigned int upA3 = *(const unsigned int*)(xp16 + (size_t)sa3 * 128 + 2 * lane);
            unsigned int upB0 = *(const unsigned int*)(xp16 + (size_t)sb0 * 128 + 2 * lane);
            unsigned int upB1 = *(const unsigned int*)(xp16 + (size_t)sb1 * 128 + 2 * lane);
            unsigned int upB2 = *(const unsigned int*)(xp16 + (size_t)sb2 * 128 + 2 * lane);
            unsigned int upB3 = *(const unsigned int*)(xp16 + (size_t)sb3 * 128 + 2 * lane);
            float m0 = e0, m1 = e1, m2 = e2, m3 = e3;
            for (int off = 16; off >= 1; off >>= 1) {
                m0 = fmaxf(m0, __shfl_xor(m0, off, 32));
                m1 = fmaxf(m1, __shfl_xor(m1, off, 32));
                m2 = fmaxf(m2, __shfl_xor(m2, off, 32));
                m3 = fmaxf(m3, __shfl_xor(m3, off, 32));
            }
            float p0 = (l32 < degh) ? __expf(e0 - m0) : 0.f;
            float p1 = (l32 < degh) ? __expf(e1 - m1) : 0.f;
            float p2 = (l32 < degh) ? __expf(e2 - m2) : 0.f;
            float p3 = (l32 < degh) ? __expf(e3 - m3) : 0.f;
            float n0 = p0, n1 = p1, n2 = p2, n3 = p3;
            for (int off = 16; off >= 1; off >>= 1) {
                n0 += __shfl_xor(n0, off, 32);
                n1 += __shfl_xor(n1, off, 32);
                n2 += __shfl_xor(n2, off, 32);
                n3 += __shfl_xor(n3, off, 32);
            }
            if (l32 == 0)
                invb[w][half] = make_float4(1.f / (n0 + 1e-16f), 1.f / (n1 + 1e-16f),
                                            1.f / (n2 + 1e-16f), 1.f / (n3 + 1e-16f));
            if (l32 < degh) {
                pb[w][half * 32 + l32] = make_float4(p0, p1, p2, p3);
                sb[w][half * 32 + l32] = s;
            }
            asm volatile("s_waitcnt lgkmcnt(0)" ::: "memory");
            __builtin_amdgcn_sched_barrier(0);
            int deg0 = __shfl(degh, 0, 64);
            int deg1 = __shfl(degh, 32, 64);
            // ---- pass 2: full wave, one dest at a time ----
#pragma unroll
            for (int tt = 0; tt < 2; ++tt) {
                int degt = tt ? deg1 : deg0;
                const float4* pbt = &pb[w][tt * 32];
                const int* sbt = &sb[w][tt * 32];
                float a0 = 0.f, a1 = 0.f;
                int j = 0;
                if (degt >= 4) {  // first block consumes the prefetched loads
                    float w0 = ((const float*)&pbt[0])[hh];
                    float w1 = ((const float*)&pbt[1])[hh];
                    float w2 = ((const float*)&pbt[2])[hh];
                    float w3 = ((const float*)&pbt[3])[hh];
                    unsigned int u0 = tt ? upB0 : upA0;
                    unsigned int u1 = tt ? upB1 : upA1;
                    unsigned int u2 = tt ? upB2 : upA2;
                    unsigned int u3 = tt ? upB3 : upA3;
                    a0 += w0 * b2f_lo(u0) + w1 * b2f_lo(u1) + w2 * b2f_lo(u2) + w3 * b2f_lo(u3);
                    a1 += w0 * b2f_hi(u0) + w1 * b2f_hi(u1) + w2 * b2f_hi(u2) + w3 * b2f_hi(u3);
                    j = 4;
                }
                for (; j + 4 <= degt; j += 4) {
                    int s0 = __builtin_amdgcn_readfirstlane(sbt[j]);
                    int s1 = __builtin_amdgcn_readfirstlane(sbt[j + 1]);
                    int s2 = __builtin_amdgcn_readfirstlane(sbt[j + 2]);
                    int s3 = __builtin_amdgcn_readfirstlane(sbt[j + 3]);
                    float w0 = ((const float*)&pbt[j])[hh];
                    float w1 = ((const float*)&pbt[j + 1])[hh];
                    float w2 = ((const float*)&pbt[j + 2])[hh];
                    float w3 = ((const float*)&pbt[j + 3])[hh];
                    unsigned int u0 = *(const unsigned int*)(xp16 + (size_t)s0 * 128 + 2 * lane);
                    unsigned int u1 = *(const unsigned int*)(xp16 + (size_t)s1 * 128 + 2 * lane);
                    unsigned int u2 = *(const unsigned int*)(xp16 + (size_t)s2 * 128 + 2 * lane);
                    unsigned int u3 = *(const unsigned int*)(xp16 + (size_t)s3 * 128 + 2 * lane);
                    a0 += w0 * b2f_lo(u0) + w1 * b2f_lo(u1) + w2 * b2f_lo(u2) + w3 * b2f_lo(u3);
                    a1 += w0 * b2f_hi(u0) + w1 * b2f_hi(u1) + w2 * b2f_hi(u2) + w3 * b2f_hi(u3);
                }
                for (; j < degt; ++j) {
                    int sj = __builtin_amdgcn_readfirstlane(sbt[j]);
                    float wj = ((const float*)&pbt[j])[hh];
                    unsigned int u = *(const unsigned int*)(xp16 + (size_t)sj * 128 + 2 * lane);
                    a0 += wj * b2f_lo(u);
                    a1 += wj * b2f_hi(u);
                }
                float inv = ((const float*)&invb[w][tt])[hh];
                float2 o = make_float2(a0 * inv + bias[2 * lane], a1 * inv + bias[2 * lane + 1]);
                *(float2*)(out + (size_t)(base + tt) * 128 + 2 * lane) = o;
                s1lo += o.x; s1hi += o.y;
                s2lo += o.x * o.x; s2hi += o.y * o.y;
            }
        } else {
            float2 oA = facc01_one(base, lane, pb[w], sb[w], xp16, a_s, a_d, rowptr, eidx,
                                   bias, out);
            s1lo += oA.x; s1hi += oA.y;
            s2lo += oA.x * oA.x; s2hi += oA.y * oA.y;
            if (have2) {
                float2 oB = facc01_one(base + 1, lane, pb[w], sb[w], xp16, a_s, a_d, rowptr,
                                       eidx, bias, out);
                s1lo += oB.x; s1hi += oB.y;
                s2lo += oB.x * oB.x; s2hi += oB.y * oB.y;
            }
        }
    }
    // ---- atomic-free BN partials: per-wave slots -> cross-wave reduce -> global row ----
    bsl1[w][2 * lane] = s1lo;
    bsl1[w][2 * lane + 1] = s1hi;
    bsl2[w][2 * lane] = s2lo;
    bsl2[w][2 * lane + 1] = s2hi;
    __syncthreads();
    if (t < 128) {
        float p1 = bsl1[0][t] + bsl1[1][t] + bsl1[2][t] + bsl1[3][t];
        float p2 = bsl2[0][t] + bsl2[1][t] + bsl2[2][t] + bsl2[3][t];
        partials[(size_t)blockIdx.x * 256 + t] = p1;
        partials[(size_t)blockIdx.x * 256 + 128 + t] = p2;
    }
}

// ---------------- BN partial reduce (high-occupancy, 4-deep pipelined) ----------------
__global__ void k_bnred(const float* __restrict__ partials, float* __restrict__ sums,
                        int nblk) {
    int c = threadIdx.x;  // 256, coalesced across a row
    int G = gridDim.x;
    float a0 = 0.f, a1 = 0.f, a2 = 0.f, a3 = 0.f;
    int b = blockIdx.x;
    for (; b + 3 * G < nblk; b += 4 * G) {
        a0 += partials[(size_t)b * 256 + c];
        a1 += partials[(size_t)(b + G) * 256 + c];
        a2 += partials[(size_t)(b + 2 * G) * 256 + c];
        a3 += partials[(size_t)(b + 3 * G) * 256 + c];
    }
    for (; b < nblk; b += G) a0 += partials[(size_t)b * 256 + c];
    atomicAdd(&sums[c], (a0 + a1) + (a2 + a3));
}

// ---------------- single-dest fused softmax+accumulate, layer 2 (full wave) ----------------
__device__ __forceinline__ void faccL2_one(int d, int lane, float4* pbw, int* sbw,
                                           const unsigned short* __restrict__ hb16,
                                           const float* __restrict__ a_s,
                                           const float* __restrict__ a_d,
                                           const int* __restrict__ rowptr,
                                           const int* __restrict__ eidx,
                                           unsigned short* __restrict__ agg16) {
    float4 ad4 = *(const float4*)(a_d + (size_t)d * 4);
    int jb = rowptr[d], je = rowptr[d + 1], deg = je - jb;
    float acc[4][2] = {{0.f, 0.f}, {0.f, 0.f}, {0.f, 0.f}, {0.f, 0.f}};
    float iv0, iv1, iv2, iv3;
    if (deg <= 64) {
        int s = 0;
        float e0 = -INFINITY, e1 = -INFINITY, e2 = -INFINITY, e3 = -INFINITY;
        if (lane < deg) {
            s = eidx[jb + lane];
            float4 as4 = *(const float4*)(a_s + (size_t)s * 4);
            e0 = lrelu(as4.x + ad4.x);
            e1 = lrelu(as4.y + ad4.y);
            e2 = lrelu(as4.z + ad4.z);
            e3 = lrelu(as4.w + ad4.w);
        }
        float m0 = e0, m1 = e1, m2 = e2, m3 = e3;
        for (int off = 32; off >= 1; off >>= 1) {
            m0 = fmaxf(m0, __shfl_xor(m0, off, 64));
            m1 = fmaxf(m1, __shfl_xor(m1, off, 64));
            m2 = fmaxf(m2, __shfl_xor(m2, off, 64));
            m3 = fmaxf(m3, __shfl_xor(m3, off, 64));
        }
        float p0 = (lane < deg) ? __expf(e0 - m0) : 0.f;
        float p1 = (lane < deg) ? __expf(e1 - m1) : 0.f;
        float p2 = (lane < deg) ? __expf(e2 - m2) : 0.f;
        float p3 = (lane < deg) ? __expf(e3 - m3) : 0.f;
        float n0 = p0, n1 = p1, n2 = p2, n3 = p3;
        for (int off = 32; off >= 1; off >>= 1) {
            n0 += __shfl_xor(n0, off, 64);
            n1 += __shfl_xor(n1, off, 64);
            n2 += __shfl_xor(n2, off, 64);
            n3 += __shfl_xor(n3, off, 64);
        }
        iv0 = 1.f / (n0 + 1e-16f);
        iv1 = 1.f / (n1 + 1e-16f);
        iv2 = 1.f / (n2 + 1e-16f);
        iv3 = 1.f / (n3 + 1e-16f);
        if (lane < deg) {
            pbw[lane] = make_float4(p0, p1, p2, p3);
            sbw[lane] = s;
        }
        asm volatile("s_waitcnt lgkmcnt(0)" ::: "memory");
        __builtin_amdgcn_sched_barrier(0);
        int j = 0;
        for (; j + 4 <= deg; j += 4) {
            int s0 = __builtin_amdgcn_readfirstlane(sbw[j]);
            int s1 = __builtin_amdgcn_readfirstlane(sbw[j + 1]);
            int s2 = __builtin_amdgcn_readfirstlane(sbw[j + 2]);
            int s3 = __builtin_amdgcn_readfirstlane(sbw[j + 3]);
            float4 w0 = pbw[j], w1 = pbw[j + 1], w2 = pbw[j + 2], w3 = pbw[j + 3];
            unsigned int u0 = *(const unsigned int*)(hb16 + (size_t)s0 * 128 + 2 * lane);
            unsigned int u1 = *(const unsigned int*)(hb16 + (size_t)s1 * 128 + 2 * lane);
            unsigned int u2 = *(const unsigned int*)(hb16 + (size_t)s2 * 128 + 2 * lane);
            unsigned int u3 = *(const unsigned int*)(hb16 + (size_t)s3 * 128 + 2 * lane);
            float lo0 = b2f_lo(u0), hi0 = b2f_hi(u0);
            float lo1 = b2f_lo(u1), hi1 = b2f_hi(u1);
            float lo2 = b2f_lo(u2), hi2 = b2f_hi(u2);
            float lo3 = b2f_lo(u3), hi3 = b2f_hi(u3);
#pragma unroll
            for (int hh = 0; hh < 4; hh++) {
                acc[hh][0] += ((const float*)&w0)[hh] * lo0 + ((const float*)&w1)[hh] * lo1 +
                              ((const float*)&w2)[hh] * lo2 + ((const float*)&w3)[hh] * lo3;
                acc[hh][1] += ((const float*)&w0)[hh] * hi0 + ((const float*)&w1)[hh] * hi1 +
                              ((const float*)&w2)[hh] * hi2 + ((const float*)&w3)[hh] * hi3;
            }
        }
        for (; j < deg; ++j) {
            int sj = __builtin_amdgcn_readfirstlane(sbw[j]);
            float4 wj = pbw[j];
            unsigned int u = *(const unsigned int*)(hb16 + (size_t)sj * 128 + 2 * lane);
            float lo = b2f_lo(u), hi = b2f_hi(u);
#pragma unroll
            for (int hh = 0; hh < 4; hh++) {
                acc[hh][0] += ((const float*)&wj)[hh] * lo;
                acc[hh][1] += ((const float*)&wj)[hh] * hi;
            }
        }
    } else {
        float m0 = -INFINITY, m1 = -INFINITY, m2 = -INFINITY, m3 = -INFINITY;
        for (int jj = jb + lane; jj < je; jj += 64) {
            int s = eidx[jj];
            float4 as4 = *(const float4*)(a_s + (size_t)s * 4);
            m0 = fmaxf(m0, lrelu(as4.x + ad4.x));
            m1 = fmaxf(m1, lrelu(as4.y + ad4.y));
            m2 = fmaxf(m2, lrelu(as4.z + ad4.z));
            m3 = fmaxf(m3, lrelu(as4.w + ad4.w));
        }
        for (int off = 32; off >= 1; off >>= 1) {
            m0 = fmaxf(m0, __shfl_xor(m0, off, 64));
            m1 = fmaxf(m1, __shfl_xor(m1, off, 64));
            m2 = fmaxf(m2, __shfl_xor(m2, off, 64));
            m3 = fmaxf(m3, __shfl_xor(m3, off, 64));
        }
        float n0 = 0.f, n1 = 0.f, n2 = 0.f, n3 = 0.f;
        for (int jj = jb + lane; jj < je; jj += 64) {
            int s = eidx[jj];
            float4 as4 = *(const float4*)(a_s + (size_t)s * 4);
            n0 += __expf(lrelu(as4.x + ad4.x) - m0);
            n1 += __expf(lrelu(as4.y + ad4.y) - m1);
            n2 += __expf(lrelu(as4.z + ad4.z) - m2);
            n3 += __expf(lrelu(as4.w + ad4.w) - m3);
        }
        for (int off = 32; off >= 1; off >>= 1) {
            n0 += __shfl_xor(n0, off, 64);
            n1 += __shfl_xor(n1, off, 64);
            n2 += __shfl_xor(n2, off, 64);
            n3 += __shfl_xor(n3, off, 64);
        }
        iv0 = 1.f / (n0 + 1e-16f);
        iv1 = 1.f / (n1 + 1e-16f);
        iv2 = 1.f / (n2 + 1e-16f);
        iv3 = 1.f / (n3 + 1e-16f);
        for (int j = jb; j < je; ++j) {
            int s = __builtin_amdgcn_readfirstlane(eidx[j]);
            float4 as4 = *(const float4*)(a_s + (size_t)s * 4);
            float w0 = __expf(lrelu(as4.x + ad4.x) - m0);
            float w1 = __expf(lrelu(as4.y + ad4.y) - m1);
            float w2 = __expf(lrelu(as4.z + ad4.z) - m2);
            float w3 = __expf(lrelu(as4.w + ad4.w) - m3);
            unsigned int u = *(const unsigned int*)(hb16 + (size_t)s * 128 + 2 * lane);
            float lo = b2f_lo(u), hi = b2f_hi(u);
            acc[0][0] += w0 * lo; acc[0][1] += w0 * hi;
            acc[1][0] += w1 * lo; acc[1][1] += w1 * hi;
            acc[2][0] += w2 * lo; acc[2][1] += w2 * hi;
            acc[3][0] += w3 * lo; acc[3][1] += w3 * hi;
        }
    }
    float iv[4] = {iv0, iv1, iv2, iv3};
#pragma unroll
    for (int hh = 0; hh < 4; hh++) {
        ushort2 o = make_ushort2(f2b(acc[hh][0] * iv[hh]), f2b(acc[hh][1] * iv[hh]));
        *(ushort2*)(agg16 + (size_t)d * 512 + hh * 128 + 2 * lane) = o;
    }
}

// ---------------- FUSED softmax + accumulation, layer 2 (2 dests per wave) ----------------
__global__ __launch_bounds__(256) void k_faccL2(const unsigned short* __restrict__ hb16,
                                                const float* __restrict__ a_s,
                                                const float* __restrict__ a_d,
                                                const int* __restrict__ rowptr,
                                                const int* __restrict__ eidx,
                                                unsigned short* __restrict__ agg16, int N) {
    __shared__ float4 pb[4][64];
    __shared__ int sb[4][64];
    __shared__ float4 invb[4][2];
    int w = threadIdx.x >> 6, lane = threadIdx.x & 63;
    int base = (blockIdx.x * 4 + w) * 2;
    if (base >= N) return;
    bool have2 = (base + 1 < N);
    int half = lane >> 5, l32 = lane & 31;
    int dh = base + (have2 ? half : 0);
    int jbh = rowptr[dh], jeh = rowptr[dh + 1];
    int degh = jeh - jbh;
    if (have2 && __all(degh <= 32)) {
        // ---- pass 1: half-wave per dest ----
        float4 ad4 = *(const float4*)(a_d + (size_t)dh * 4);
        int s = 0;
        float e0 = -INFINITY, e1 = -INFINITY, e2 = -INFINITY, e3 = -INFINITY;
        if (l32 < degh) {
            s = eidx[jbh + l32];
            float4 as4 = *(const float4*)(a_s + (size_t)s * 4);
            e0 = lrelu(as4.x + ad4.x);
            e1 = lrelu(as4.y + ad4.y);
            e2 = lrelu(as4.z + ad4.z);
            e3 = lrelu(as4.w + ad4.w);
        }
        // prefetch first 4-edge block per dest
        int sa0 = __builtin_amdgcn_readfirstlane(__shfl(s, 0, 64));
        int sa1 = __builtin_amdgcn_readfirstlane(__shfl(s, 1, 64));
        int sa2 = __builtin_amdgcn_readfirstlane(__shfl(s, 2, 64));
        int sa3 = __builtin_amdgcn_readfirstlane(__shfl(s, 3, 64));
        int sb0 = __builtin_amdgcn_readfirstlane(__shfl(s, 32, 64));
        int sb1 = __builtin_amdgcn_readfirstlane(__shfl(s, 33, 64));
        int sb2 = __builtin_amdgcn_readfirstlane(__shfl(s, 34, 64));
        int sb3 = __builtin_amdgcn_readfirstlane(__shfl(s, 35, 64));
        unsigned int upA0 = *(const unsigned int*)(hb16 + (size_t)sa0 * 128 + 2 * lane);
        unsigned int upA1 = *(const unsigned int*)(hb16 + (size_t)sa1 * 128 + 2 * lane);
        unsigned int upA2 = *(const unsigned int*)(hb16 + (size_t)sa2 * 128 + 2 * lane);
        unsigned int upA3 = *(const unsigned int*)(hb16 + (size_t)sa3 * 128 + 2 * lane);
        unsigned int upB0 = *(const unsigned int*)(hb16 + (size_t)sb0 * 128 + 2 * lane);
        unsigned int upB1 = *(const unsigned int*)(hb16 + (size_t)sb1 * 128 + 2 * lane);
        unsigned int upB2 = *(const unsigned int*)(hb16 + (size_t)sb2 * 128 + 2 * lane);
        unsigned int upB3 = *(const unsigned int*)(hb16 + (size_t)sb3 * 128 + 2 * lane);
        float m0 = e0, m1 = e1, m2 = e2, m3 = e3;
        for (int off = 16; off >= 1; off >>= 1) {
            m0 = fmaxf(m0, __shfl_xor(m0, off, 32));
            m1 = fmaxf(m1, __shfl_xor(m1, off, 32));
            m2 = fmaxf(m2, __shfl_xor(m2, off, 32));
            m3 = fmaxf(m3, __shfl_xor(m3, off, 32));
        }
        float p0 = (l32 < degh) ? __expf(e0 - m0) : 0.f;
        float p1 = (l32 < degh) ? __expf(e1 - m1) : 0.f;
        float p2 = (l32 < degh) ? __expf(e2 - m2) : 0.f;
        float p3 = (l32 < degh) ? __expf(e3 - m3) : 0.f;
        float n0 = p0, n1 = p1, n2 = p2, n3 = p3;
        for (int off = 16; off >= 1; off >>= 1) {
            n0 += __shfl_xor(n0, off, 32);
            n1 += __shfl_xor(n1, off, 32);
            n2 += __shfl_xor(n2, off, 32);
            n3 += __shfl_xor(n3, off, 32);
        }
        if (l32 == 0)
            invb[w][half] = make_float4(1.f / (n0 + 1e-16f), 1.f / (n1 + 1e-16f),
                                        1.f / (n2 + 1e-16f), 1.f / (n3 + 1e-16f));
        if (l32 < degh) {
            pb[w][half * 32 + l32] = make_float4(p0, p1, p2, p3);
            sb[w][half * 32 + l32] = s;
        }
        asm volatile("s_waitcnt lgkmcnt(0)" ::: "memory");
        __builtin_amdgcn_sched_barrier(0);
        int deg0 = __shfl(degh, 0, 64);
        int deg1 = __shfl(degh, 32, 64);
        // ---- pass 2: full wave, one dest at a time ----
#pragma unroll
        for (int t = 0; t < 2; ++t) {
            int degt = t ? deg1 : deg0;
            const float4* pbt = &pb[w][t * 32];
            const int* sbt = &sb[w][t * 32];
            float acc[4][2] = {{0.f, 0.f}, {0.f, 0.f}, {0.f, 0.f}, {0.f, 0.f}};
            int j = 0;
            if (degt >= 4) {  // first block consumes the prefetched loads
                float4 w0 = pbt[0], w1 = pbt[1], w2 = pbt[2], w3 = pbt[3];
                unsigned int u0 = t ? upB0 : upA0;
                unsigned int u1 = t ? upB1 : upA1;
                unsigned int u2 = t ? upB2 : upA2;
                unsigned int u3 = t ? upB3 : upA3;
                float lo0 = b2f_lo(u0), hi0 = b2f_hi(u0);
                float lo1 = b2f_lo(u1), hi1 = b2f_hi(u1);
                float lo2 = b2f_lo(u2), hi2 = b2f_hi(u2);
                float lo3 = b2f_lo(u3), hi3 = b2f_hi(u3);
#pragma unroll
                for (int hh = 0; hh < 4; hh++) {
                    acc[hh][0] += ((const float*)&w0)[hh] * lo0 + ((const float*)&w1)[hh] * lo1 +
                                  ((const float*)&w2)[hh] * lo2 + ((const float*)&w3)[hh] * lo3;
                    acc[hh][1] += ((const float*)&w0)[hh] * hi0 + ((const float*)&w1)[hh] * hi1 +
                                  ((const float*)&w2)[hh] * hi2 + ((const float*)&w3)[hh] * hi3;
                }
                j = 4;
            }
            for (; j + 4 <= degt; j += 4) {
                int s0 = __builtin_amdgcn_readfirstlane(sbt[j]);
                int s1 = __builtin_amdgcn_readfirstlane(sbt[j + 1]);
                int s2 = __builtin_amdgcn_readfirstlane(sbt[j + 2]);
                int s3 = __builtin_amdgcn_readfirstlane(sbt[j + 3]);
                float4 w0 = pbt[j], w1 = pbt[j + 1], w2 = pbt[j + 2], w3 = pbt[j + 3];
                unsigned int u0 = *(const unsigned int*)(hb16 + (size_t)s0 * 128 + 2 * lane);
                unsigned int u1 = *(const unsigned int*)(hb16 + (size_t)s1 * 128 + 2 * lane);
                unsigned int u2 = *(const unsigned int*)(hb16 + (size_t)s2 * 128 + 2 * lane);
                unsigned int u3 = *(const unsigned int*)(hb16 + (size_t)s3 * 128 + 2 * lane);
                float lo0 = b2f_lo(u0), hi0 = b2f_hi(u0);
                float lo1 = b2f_lo(u1), hi1 = b2f_hi(u1);
                float lo2 = b2f_lo(u2), hi2 = b2f_hi(u2);
                float lo3 = b2f_lo(u3), hi3 = b2f_hi(u3);
#pragma unroll
                for (int hh = 0; hh < 4; hh++) {
                    acc[hh][0] += ((const float*)&w0)[hh] * lo0 + ((const float*)&w1)[hh] * lo1 +
                                  ((const float*)&w2)[hh] * lo2 + ((const float*)&w3)[hh] * lo3;
                    acc[hh][1] += ((const float*)&w0)[hh] * hi0 + ((const float*)&w1)[hh] * hi1 +
                                  ((const float*)&w2)[hh] * hi2 + ((const float*)&w3)[hh] * hi3;
                }
            }
            for (; j < degt; ++j) {
                int sj = __builtin_amdgcn_readfirstlane(sbt[j]);
                float4 wj = pbt[j];
                unsigned int u = *(const unsigned int*)(hb16 + (size_t)sj * 128 + 2 * lane);
                float lo = b2f_lo(u), hi = b2f_hi(u);
#pragma unroll
                for (int hh = 0; hh < 4; hh++) {
                    acc[hh][0] += ((const float*)&wj)[hh] * lo;
                    acc[hh][1] += ((const float*)&wj)[hh] * hi;
                }
            }
            float4 ivv = invb[w][t];
            const float* iv = (const float*)&ivv;
#pragma unroll
            for (int hh = 0; hh < 4; hh++) {
                ushort2 o = make_ushort2(f2b(acc[hh][0] * iv[hh]), f2b(acc[hh][1] * iv[hh]));
                *(ushort2*)(agg16 + (size_t)(base + t) * 512 + hh * 128 + 2 * lane) = o;
            }
        }
    } else {
        faccL2_one(base, lane, pb[w], sb[w], hb16, a_s, a_d, rowptr, eidx, agg16);
        if (have2)
            faccL2_one(base + 1, lane, pb[w], sb[w], hb16, a_s, a_d, rowptr, eidx, agg16);
    }
}

// ---------------- batch norm apply ----------------
__global__ void k_bnapply(float* __restrict__ x, unsigned short* __restrict__ out16,
                          const float* __restrict__ sums, const float* __restrict__ gamma,
                          const float* __restrict__ beta, int N, int elu, int writex) {
    int idx = blockIdx.x * blockDim.x + threadIdx.x;
    if (idx >= N * 32) return;
    float4 v = ((float4*)x)[idx];
    int colb = (idx & 31) * 4;
    float invN = 1.f / (float)N;
#pragma unroll
    for (int j = 0; j < 4; j++) {
        int col = colb + j;
        float mu = sums[col] * invN;
        float var = sums[128 + col] * invN - mu * mu;
        float y = (((float*)&v)[j] - mu) * rsqrtf(var + EPS_BN) * gamma[col] + beta[col];
        if (elu) y = y > 0.f ? y : __expf(y) - 1.f;
        ((float*)&v)[j] = y;
    }
    if (writex) ((float4*)x)[idx] = v;
    if (out16) {
        ushort4 o = make_ushort4(f2b(v.x), f2b(v.y), f2b(v.z), f2b(v.w));
        ((ushort4*)out16)[idx] = o;
    }
}

// ---------------- fused BN+ELU+bf16 + layer-2 attention scores (layer 1 only) ----------------
__global__ __launch_bounds__(256) void k_bnapply_att(const float* __restrict__ x,
                                                     unsigned short* __restrict__ out16,
                                                     const float* __restrict__ sums,
                                                     const float* __restrict__ gamma,
                                                     const float* __restrict__ beta,
                                                     const float* __restrict__ Wt,
                                                     float* __restrict__ a_s,
                                                     float* __restrict__ a_d, int N) {
    int wid = (blockIdx.x * blockDim.x + threadIdx.x) >> 6;
    int lane = threadIdx.x & 63;
    if (wid >= N) return;
    float invN = 1.f / (float)N;
    int c0 = lane, c1 = 64 + lane;
    float v0 = x[(size_t)wid * 128 + c0];
    float v1 = x[(size_t)wid * 128 + c1];
    float mu0 = sums[c0] * invN;
    float var0 = sums[128 + c0] * invN - mu0 * mu0;
    float y0 = (v0 - mu0) * rsqrtf(var0 + EPS_BN) * gamma[c0] + beta[c0];
    float mu1 = sums[c1] * invN;
    float var1 = sums[128 + c1] * invN - mu1 * mu1;
    float y1 = (v1 - mu1) * rsqrtf(var1 + EPS_BN) * gamma[c1] + beta[c1];
    y0 = y0 > 0.f ? y0 : __expf(y0) - 1.f;
    y1 = y1 > 0.f ? y1 : __expf(y1) - 1.f;
    out16[(size_t)wid * 128 + c0] = f2b(y0);
    out16[(size_t)wid * 128 + c1] = f2b(y1);
    float ts[4], td[4];
#pragma unroll
    for (int hh = 0; hh < 4; hh++) {
        ts[hh] = y0 * Wt[hh * 128 + lane] + y1 * Wt[hh * 128 + 64 + lane];
        td[hh] = y0 * Wt[512 + hh * 128 + lane] + y1 * Wt[512 + hh * 128 + 64 + lane];
    }
    for (int m = 32; m >= 1; m >>= 1) {
#pragma unroll
        for (int hh = 0; hh < 4; hh++) {
            ts[hh] += __shfl_xor(ts[hh], m, 64);
            td[hh] += __shfl_xor(td[hh], m, 64);
        }
    }
    if (lane == 0) {
#pragma unroll
        for (int hh = 0; hh < 4; hh++) {
            a_s[wid * 4 + hh] = ts[hh];
            a_d[wid * 4 + hh] = td[hh];
        }
    }
}

// ---------------- launch ----------------
extern "C" void kernel_launch(void* const* d_in, const int* in_sizes, int n_in,
                              void* d_out, int out_size, void* d_ws, size_t ws_size,
                              hipStream_t stream) {
    const float* x = (const float*)d_in[0];
    const int* ei_raw = (const int*)d_in[1];
    const float* W0 = (const float*)d_in[2];
    const float* as0 = (const float*)d_in[3];
    const float* ad0 = (const float*)d_in[4];
    const float* b0 = (const float*)d_in[5];
    const float* g0 = (const float*)d_in[6];
    const float* be0 = (const float*)d_in[7];
    const float* W1 = (const float*)d_in[8];
    const float* as1 = (const float*)d_in[9];
    const float* ad1 = (const float*)d_in[10];
    const float* b1 = (const float*)d_in[11];
    const float* g1 = (const float*)d_in[12];
    const float* be1 = (const float*)d_in[13];
    const float* W2 = (const float*)d_in[14];
    const float* as2 = (const float*)d_in[15];
    const float* ad2 = (const float*)d_in[16];
    const float* g2v = (const float*)d_in[18];
    const float* be2 = (const float*)d_in[19];

    const int N = in_sizes[0] / 128;
    const int E = in_sizes[1] / 2;
    const int gw2 = (N + 7) / 8;

    // workspace carve (256B aligned)
    char* p = (char*)d_ws;
    auto alloc = [&](size_t bytes) {
        void* r = (void*)p;
        p += (bytes + 255) & ~(size_t)255;
        return r;
    };
    float* hbuf = (float*)alloc((size_t)N * 128 * 4);
    unsigned short* xb = (unsigned short*)alloc((size_t)N * 128 * 2);
    unsigned short* xp16 = (unsigned short*)alloc((size_t)N * 128 * 2);
    unsigned short* hb16 = (unsigned short*)alloc((size_t)N * 128 * 2);
    unsigned short* agg16 = (unsigned short*)alloc((size_t)N * 512 * 2);
    float* As = (float*)alloc((size_t)N * 4 * 4);
    float* Ad = (float*)alloc((size_t)N * 4 * 4);
    int* deg = (int*)alloc((size_t)N * 4);
    int* rowptr = (int*)alloc((size_t)(N + 1) * 4);
    int* bsum = (int*)alloc(1024);
    int* eidx = (int*)alloc((size_t)(E + N) * 4);
    float* bns = (float*)alloc(768 * 4);  // 3 slots of 256
    int* flag = (int*)alloc(256);
    float* Wt = (float*)alloc(1024 * 4);
    unsigned short* WT0 = (unsigned short*)alloc((size_t)128 * 128 * 2);
    unsigned short* WT1 = (unsigned short*)alloc((size_t)128 * 128 * 2);
    unsigned short* WT2 = (unsigned short*)alloc((size_t)128 * 512 * 2);
    float* partials = (float*)alloc((size_t)gw2 * 256 * 4);
    int2* pairs = (int2*)alloc((size_t)NBUK * BCAP * 8);
    int* gcnt = (int*)alloc(NBUK * 4);
    if ((size_t)(p - (char*)d_ws) > ws_size) return;

    const int nb = (N + 255) / 256;
    const int gw = (N + 3) / 4;
    const int gt = (N + 63) / 64;
    const int nbuk_used = (N + (1 << BSHIFT) - 1) >> BSHIFT;
    const int binB = (E + 1023) / 1024;
    const int prepB = 640 + (N * 32 + 255) / 256;

    // --- CSR build (bucketed, LDS-sorted); detect zeroes gcnt + bns; prep fused into bin ---
    k_detect64<<<1, 64, 0, stream>>>(ei_raw, flag, 2 * E, gcnt, bns);
    k_bin_prep<<<binB + prepB, 256, 0, stream>>>(ei_raw, flag, E, gcnt, pairs, binB, W0, W1,
                                                 W2, as2, ad2, WT0, WT1, WT2, Wt, x, xb,
                                                 N * 32);
    k_bdeg2<<<nbuk_used, 256, 0, stream>>>(pairs, gcnt, deg, N);
    k_scan1<<<nb, 256, 0, stream>>>(deg, rowptr, bsum, N);
    k_scan3<<<nb, 256, 0, stream>>>(rowptr, bsum, N);
    k_bsort<<<nbuk_used, 256, 0, stream>>>(pairs, gcnt, rowptr, eidx, N);

    // --- layer 0 (GEMM fuses attention scores; softmax + BN partials fused into accumulate) ---
    k_tgemm<128, false><<<gt, 256, 0, stream>>>(xb, (const float*)nullptr,
                                                (const float*)nullptr, (const float*)nullptr,
                                                (const float*)nullptr, WT0, (float*)nullptr,
                                                xp16, as0, ad0, As, Ad, N, (float*)nullptr);
    k_facc01<<<gw2, 256, 0, stream>>>(xp16, As, Ad, rowptr, eidx, b0, hbuf, partials, N);
    k_bnred<<<256, 256, 0, stream>>>(partials, bns, gw2);
    // L0 BN+ELU+cast fused into L1 GEMM A-load (hb16 round-trip removed)

    // --- layer 1 (A = BN(hbuf) inline; BN+ELU fused with layer-2 attention scores) ---
    k_tgemm<128, true><<<gt, 256, 0, stream>>>((const unsigned short*)nullptr, hbuf, bns, g0,
                                               be0, WT1, (float*)nullptr, xp16, as1, ad1, As,
                                               Ad, N, (float*)nullptr);
    k_facc01<<<gw2, 256, 0, stream>>>(xp16, As, Ad, rowptr, eidx, b1, hbuf, partials, N);
    k_bnred<<<256, 256, 0, stream>>>(partials, bns + 256, gw2);
    k_bnapply_att<<<gw, 256, 0, stream>>>(hbuf, hb16, bns + 256, g1, be1, Wt, As, Ad, N);

    // --- layer 2 (BN partials fused into GEMM epilogue, atomic-free) ---
    float* outf = (float*)d_out;
    k_faccL2<<<gw2, 256, 0, stream>>>(hb16, As, Ad, rowptr, eidx, agg16, N);
    k_tgemm<512, false><<<gt, 256, 0, stream>>>(agg16, (const float*)nullptr,
                                                (const float*)nullptr, (const float*)nullptr,
                                                (const float*)nullptr, WT2, outf,
                                                (unsigned short*)nullptr, (const float*)nullptr,
                                                (const float*)nullptr, (float*)nullptr,
                                                (float*)nullptr, N, partials);
    k_bnred<<<256, 256, 0, stream>>>(partials, bns + 512, gt);
    k_bnapply<<<(N * 32 + 255) / 256, 256, 0, stream>>>(outf, (unsigned short*)nullptr,
                                                        bns + 512, g2v, be2, N, 0, 1);
}